// Round 1
// baseline (829.741 us; speedup 1.0000x reference)
//
#include <hip/hip_runtime.h>
#include <hip/hip_bf16.h>
#include <cstdint>

typedef __bf16 bf16x8 __attribute__((ext_vector_type(8)));
typedef float  f32x4  __attribute__((ext_vector_type(4)));

// ---------------- degree count (in-degree over dst) ----------------
__global__ void count_deg_kernel(const int* __restrict__ dst, int* __restrict__ cnt, int E) {
    int e = blockIdx.x * blockDim.x + threadIdx.x;
    if (e < E) atomicAdd(&cnt[dst[e]], 1);
}

// ---------------- single-block exclusive scan + dinv ----------------
__global__ __launch_bounds__(1024) void scan_kernel(const int* __restrict__ cnt,
                                                    int* __restrict__ offsets,
                                                    int* __restrict__ cursor,
                                                    float* __restrict__ dinv, int N) {
    __shared__ int sums[1024];
    int t = threadIdx.x;
    int per = (N + 1023) >> 10;
    int lo = t * per, hi = min(lo + per, N);
    int s = 0;
    for (int i = lo; i < hi; ++i) s += cnt[i];
    sums[t] = s;
    __syncthreads();
    for (int off = 1; off < 1024; off <<= 1) {
        int v = (t >= off) ? sums[t - off] : 0;
        __syncthreads();
        sums[t] += v;
        __syncthreads();
    }
    int run = (t > 0) ? sums[t - 1] : 0;
    for (int i = lo; i < hi; ++i) {
        offsets[i] = run;
        cursor[i]  = run;
        int c = cnt[i];
        dinv[i] = rsqrtf((float)(c + 1));   // +1 = self-loop; deg >= 1 always
        run += c;
    }
    if (t == 1023) offsets[N] = run;
}

// ---------------- CSR fill (counting sort by dst) ----------------
__global__ void fill_csr_kernel(const int* __restrict__ src, const int* __restrict__ dst,
                                int* __restrict__ cursor, int* __restrict__ csr_src, int E) {
    int e = blockIdx.x * blockDim.x + threadIdx.x;
    if (e >= E) return;
    int pos = atomicAdd(&cursor[dst[e]], 1);
    csr_src[pos] = src[e];
}

// ---------------- convert f32 -> bf16 (vectorized x4) ----------------
__global__ void cvt_f32_bf16_kernel(const float* __restrict__ in,
                                    __hip_bfloat16* __restrict__ out, int n4) {
    int i = blockIdx.x * blockDim.x + threadIdx.x;
    if (i >= n4) return;
    float4 v = reinterpret_cast<const float4*>(in)[i];
    __hip_bfloat16 b0 = __float2bfloat16(v.x);
    __hip_bfloat16 b1 = __float2bfloat16(v.y);
    __hip_bfloat16 b2 = __float2bfloat16(v.z);
    __hip_bfloat16 b3 = __float2bfloat16(v.w);
    ushort4 o;
    o.x = __builtin_bit_cast(unsigned short, b0);
    o.y = __builtin_bit_cast(unsigned short, b1);
    o.z = __builtin_bit_cast(unsigned short, b2);
    o.w = __builtin_bit_cast(unsigned short, b3);
    reinterpret_cast<ushort4*>(out)[i] = o;
}

// ---------------- convert all weight matrices, pad decoder to 48 rows ----------------
__global__ void cvt_weights_kernel(const float* __restrict__ encW, const float* __restrict__ W1,
                                   const float* __restrict__ W2,   const float* __restrict__ decW,
                                   __hip_bfloat16* __restrict__ encWb, __hip_bfloat16* __restrict__ W1b,
                                   __hip_bfloat16* __restrict__ W2b,   __hip_bfloat16* __restrict__ decWb) {
    int i = blockIdx.x * blockDim.x + threadIdx.x;
    if (i < 16384)      encWb[i]        = __float2bfloat16(encW[i]);
    else if (i < 32768) W1b[i - 16384]  = __float2bfloat16(W1[i - 16384]);
    else if (i < 49152) W2b[i - 32768]  = __float2bfloat16(W2[i - 32768]);
    else if (i < 49152 + 48 * 128) {
        int j = i - 49152;
        float v = (j < 40 * 128) ? decW[j] : 0.f;
        decWb[j] = __float2bfloat16(v);
    }
}

// ---------------- GEMM: out[M x ncols] = A[M x 128] @ W[ncols x 128]^T (+bias) ----------------
// MFMA 16x16x32 bf16. One wave = 16 rows x (16*NCT) cols. Block = 4 waves = 64 rows.
template<int NCT, bool OUT_F32>
__global__ __launch_bounds__(256) void gemm_bf16_k128(const __hip_bfloat16* __restrict__ A,
                                                      const __hip_bfloat16* __restrict__ W,
                                                      const float* __restrict__ bias,
                                                      void* __restrict__ out,
                                                      int M, int ldout, int ncols) {
    int lane = threadIdx.x & 63;
    int wave = threadIdx.x >> 6;
    int row0 = blockIdx.x * 64 + wave * 16;

    int arow = row0 + (lane & 15);
    if (arow >= M) arow = M - 1;                 // clamp; stores are guarded
    int kgrp = lane >> 4;                        // 0..3

    const bf16x8* Arow = reinterpret_cast<const bf16x8*>(A + (size_t)arow * 128);
    bf16x8 afrag[4];
#pragma unroll
    for (int c = 0; c < 4; ++c) afrag[c] = Arow[4 * c + kgrp];

    f32x4 acc[NCT];
#pragma unroll
    for (int t = 0; t < NCT; ++t) acc[t] = {0.f, 0.f, 0.f, 0.f};

#pragma unroll
    for (int c = 0; c < 4; ++c) {
#pragma unroll
        for (int t = 0; t < NCT; ++t) {
            int wrow = t * 16 + (lane & 15);
            bf16x8 bfrag = reinterpret_cast<const bf16x8*>(W + (size_t)wrow * 128)[4 * c + kgrp];
            acc[t] = __builtin_amdgcn_mfma_f32_16x16x32_bf16(afrag[c], bfrag, acc[t], 0, 0, 0);
        }
    }

    int rbase = row0 + kgrp * 4;                 // C/D: row=(lane>>4)*4+i, col=(lane&15)+16t
#pragma unroll
    for (int t = 0; t < NCT; ++t) {
#pragma unroll
        for (int i = 0; i < 4; ++i) {
            int r = rbase + i;
            int cidx = t * 16 + (lane & 15);
            if (r < M && cidx < ncols) {
                float v = acc[t][i];
                if (bias) v += bias[cidx];
                if (OUT_F32)
                    ((float*)out)[(size_t)r * ldout + cidx] = v;
                else
                    ((__hip_bfloat16*)out)[(size_t)r * ldout + cidx] = __float2bfloat16(v);
            }
        }
    }
}

// ---------------- aggregation: out[d] = relu(dinv[d]*(sum_s dinv[s]*h[s] + dinv[d]*h[d]) + b) ----------------
// One wave per dst node; lane owns cols {2*lane, 2*lane+1}.
__global__ __launch_bounds__(256) void agg_kernel(const __hip_bfloat16* __restrict__ h,
                                                  const int* __restrict__ csr_src,
                                                  const int* __restrict__ offsets,
                                                  const float* __restrict__ dinv,
                                                  const float* __restrict__ bias,
                                                  __hip_bfloat16* __restrict__ out, int N) {
    int wid  = (blockIdx.x * blockDim.x + threadIdx.x) >> 6;
    int lane = threadIdx.x & 63;
    if (wid >= N) return;
    int d = wid;
    int bc = lane * 2;

    float dd = dinv[d];
    __hip_bfloat162 hv = *reinterpret_cast<const __hip_bfloat162*>(&h[(size_t)d * 128 + bc]);
    float2 hf = __bfloat1622float2(hv);
    float ax = dd * hf.x, ay = dd * hf.y;       // self-loop term (gets another dd below)

    int j0 = offsets[d], j1 = offsets[d + 1];
    int j = j0;
    for (; j + 1 < j1; j += 2) {                 // 2-wide unroll: overlap the two gathers
        int s0 = csr_src[j], s1 = csr_src[j + 1];
        float w0 = dinv[s0], w1 = dinv[s1];
        __hip_bfloat162 v0 = *reinterpret_cast<const __hip_bfloat162*>(&h[(size_t)s0 * 128 + bc]);
        __hip_bfloat162 v1 = *reinterpret_cast<const __hip_bfloat162*>(&h[(size_t)s1 * 128 + bc]);
        float2 f0 = __bfloat1622float2(v0);
        float2 f1 = __bfloat1622float2(v1);
        ax += w0 * f0.x + w1 * f1.x;
        ay += w0 * f0.y + w1 * f1.y;
    }
    if (j < j1) {
        int s0 = csr_src[j];
        float w0 = dinv[s0];
        __hip_bfloat162 v0 = *reinterpret_cast<const __hip_bfloat162*>(&h[(size_t)s0 * 128 + bc]);
        float2 f0 = __bfloat1622float2(v0);
        ax += w0 * f0.x;
        ay += w0 * f0.y;
    }

    float2 bb = *reinterpret_cast<const float2*>(&bias[bc]);
    float ox = fmaxf(dd * ax + bb.x, 0.f);
    float oy = fmaxf(dd * ay + bb.y, 0.f);
    out[(size_t)d * 128 + bc]     = __float2bfloat16(ox);
    out[(size_t)d * 128 + bc + 1] = __float2bfloat16(oy);
}

// ---------------- log_softmax over 40 cols; one wave per row ----------------
__global__ __launch_bounds__(256) void logsoftmax_kernel(const float* __restrict__ logits,
                                                         float* __restrict__ out, int N) {
    int wid  = (blockIdx.x * blockDim.x + threadIdx.x) >> 6;
    int lane = threadIdx.x & 63;
    if (wid >= N) return;
    float v = (lane < 40) ? logits[(size_t)wid * 40 + lane] : -INFINITY;
    float m = v;
#pragma unroll
    for (int o = 32; o; o >>= 1) m = fmaxf(m, __shfl_xor(m, o));
    float e = (lane < 40) ? __expf(v - m) : 0.f;
    float s = e;
#pragma unroll
    for (int o = 32; o; o >>= 1) s += __shfl_xor(s, o);
    float lse = __logf(s);
    if (lane < 40) out[(size_t)wid * 40 + lane] = v - m - lse;
}

extern "C" void kernel_launch(void* const* d_in, const int* in_sizes, int n_in,
                              void* d_out, int out_size, void* d_ws, size_t ws_size,
                              hipStream_t stream) {
    const float* X    = (const float*)d_in[0];
    const int*   ei   = (const int*)d_in[1];
    const float* encW = (const float*)d_in[2];
    const float* encb = (const float*)d_in[3];
    const float* W1   = (const float*)d_in[4];
    const float* b1   = (const float*)d_in[5];
    const float* W2   = (const float*)d_in[6];
    const float* b2   = (const float*)d_in[7];
    const float* decW = (const float*)d_in[8];
    const float* decb = (const float*)d_in[9];

    const int N = in_sizes[0] / 128;
    const int E = in_sizes[1] / 2;
    const int* src = ei;
    const int* dst = ei + E;

    uint8_t* p = (uint8_t*)d_ws;
    auto carve = [&](size_t bytes) -> void* {
        uint8_t* r = p;
        p += (bytes + 255) & ~(size_t)255;
        return (void*)r;
    };
    int*   deg_cnt = (int*)carve((size_t)N * 4);
    int*   offsets = (int*)carve((size_t)(N + 1) * 4);
    int*   cursor  = (int*)carve((size_t)N * 4);
    float* dinv    = (float*)carve((size_t)N * 4);
    int*   csr_src = (int*)carve((size_t)E * 4);
    __hip_bfloat16* encWb = (__hip_bfloat16*)carve(16384 * 2);
    __hip_bfloat16* W1b   = (__hip_bfloat16*)carve(16384 * 2);
    __hip_bfloat16* W2b   = (__hip_bfloat16*)carve(16384 * 2);
    __hip_bfloat16* decWb = (__hip_bfloat16*)carve(48 * 128 * 2);
    __hip_bfloat16* xb    = (__hip_bfloat16*)carve((size_t)N * 128 * 2);
    __hip_bfloat16* hb    = (__hip_bfloat16*)carve((size_t)N * 128 * 2);
    float* logits = (float*)hb;   // hb is free by decoder time; 16MB <= 25.6MB

    // --- graph structure (recomputed every call; deterministic inputs) ---
    hipMemsetAsync(deg_cnt, 0, (size_t)N * 4, stream);
    count_deg_kernel<<<(E + 255) / 256, 256, 0, stream>>>(dst, deg_cnt, E);
    scan_kernel<<<1, 1024, 0, stream>>>(deg_cnt, offsets, cursor, dinv, N);
    fill_csr_kernel<<<(E + 255) / 256, 256, 0, stream>>>(src, dst, cursor, csr_src, E);

    // --- dtype conversions ---
    cvt_weights_kernel<<<(49152 + 48 * 128 + 255) / 256, 256, 0, stream>>>(
        encW, W1, W2, decW, encWb, W1b, W2b, decWb);
    int n4 = N * 128 / 4;
    cvt_f32_bf16_kernel<<<(n4 + 255) / 256, 256, 0, stream>>>(X, hb, n4);   // hb <- X(bf16)

    int gblocks = (N + 63) / 64;
    // encoder: xb = X @ encW^T + encb
    gemm_bf16_k128<8, false><<<gblocks, 256, 0, stream>>>(hb, encWb, encb, xb, N, 128, 128);
    // conv1: hb = xb @ W1^T ; xb = relu(agg(hb) + b1)
    gemm_bf16_k128<8, false><<<gblocks, 256, 0, stream>>>(xb, W1b, nullptr, hb, N, 128, 128);
    agg_kernel<<<(N + 3) / 4, 256, 0, stream>>>(hb, csr_src, offsets, dinv, b1, xb, N);
    // conv2
    gemm_bf16_k128<8, false><<<gblocks, 256, 0, stream>>>(xb, W2b, nullptr, hb, N, 128, 128);
    agg_kernel<<<(N + 3) / 4, 256, 0, stream>>>(hb, csr_src, offsets, dinv, b2, xb, N);
    // decoder + log_softmax
    gemm_bf16_k128<3, true><<<gblocks, 256, 0, stream>>>(xb, decWb, decb, logits, N, 40, 40);
    logsoftmax_kernel<<<(N + 3) / 4, 256, 0, stream>>>(logits, (float*)d_out, N);
}

// Round 2
// 565.795 us; speedup vs baseline: 1.4665x; 1.4665x over previous
//
#include <hip/hip_runtime.h>
#include <hip/hip_bf16.h>
#include <cstdint>

typedef __bf16 bf16x8 __attribute__((ext_vector_type(8)));
typedef float  f32x4  __attribute__((ext_vector_type(4)));

#define SCAN_ELEMS 4096   // elements per block in the scan (256 thr x 16)

// ---------------- degree count (in-degree over dst) ----------------
__global__ void count_deg_kernel(const int* __restrict__ dst, int* __restrict__ cnt, int E) {
    int e = blockIdx.x * blockDim.x + threadIdx.x;
    if (e < E) atomicAdd(&cnt[dst[e]], 1);
}

// ---------------- scan phase A: per-block partial sums ----------------
__global__ __launch_bounds__(256) void scan_phaseA(const int* __restrict__ cnt,
                                                   int* __restrict__ bsums, int N) {
    int t = threadIdx.x;
    int base = blockIdx.x * SCAN_ELEMS + t * 16;
    int s = 0;
#pragma unroll
    for (int v = 0; v < 4; ++v) {
        int idx = base + v * 4;
        if (idx + 3 < N) {
            int4 d = *reinterpret_cast<const int4*>(&cnt[idx]);
            s += d.x + d.y + d.z + d.w;
        } else {
#pragma unroll
            for (int k = 0; k < 4; ++k) if (idx + k < N) s += cnt[idx + k];
        }
    }
#pragma unroll
    for (int o = 32; o; o >>= 1) s += __shfl_down(s, o);
    __shared__ int ws[4];
    if ((t & 63) == 0) ws[t >> 6] = s;
    __syncthreads();
    if (t == 0) bsums[blockIdx.x] = ws[0] + ws[1] + ws[2] + ws[3];
}

// ---------------- scan phase B: exclusive scan of block sums (1 wave) ----------------
__global__ void scan_phaseB(int* __restrict__ bsums, int nb, int* __restrict__ offsetsN, int E) {
    int t = threadIdx.x;                      // 64 threads
    int orig = (t < nb) ? bsums[t] : 0;
    int v = orig;
#pragma unroll
    for (int o = 1; o < 64; o <<= 1) {
        int u = __shfl_up(v, o);
        if (t >= o) v += u;
    }
    if (t < nb) bsums[t] = v - orig;          // exclusive
    if (t == 0) *offsetsN = E;                // offsets[N] = total edges
}

// ---------------- scan phase C: write offsets / cursor / dinv ----------------
__global__ __launch_bounds__(256) void scan_phaseC(const int* __restrict__ cnt,
                                                   const int* __restrict__ bsums,
                                                   int* __restrict__ offsets,
                                                   int* __restrict__ cursor,
                                                   float* __restrict__ dinv, int N) {
    int t = threadIdx.x;
    int base = blockIdx.x * SCAN_ELEMS + t * 16;
    int loc[16];
    int s = 0;
#pragma unroll
    for (int v = 0; v < 4; ++v) {
        int idx = base + v * 4;
        if (idx + 3 < N) {
            int4 d = *reinterpret_cast<const int4*>(&cnt[idx]);
            loc[v * 4 + 0] = d.x; loc[v * 4 + 1] = d.y;
            loc[v * 4 + 2] = d.z; loc[v * 4 + 3] = d.w;
        } else {
#pragma unroll
            for (int k = 0; k < 4; ++k) loc[v * 4 + k] = (idx + k < N) ? cnt[idx + k] : 0;
        }
        s += loc[v * 4] + loc[v * 4 + 1] + loc[v * 4 + 2] + loc[v * 4 + 3];
    }
    // block-wide exclusive scan of per-thread sums
    int lane = t & 63, w = t >> 6;
    int v = s;
#pragma unroll
    for (int o = 1; o < 64; o <<= 1) {
        int u = __shfl_up(v, o);
        if (lane >= o) v += u;
    }
    __shared__ int wsum[4];
    if (lane == 63) wsum[w] = v;
    __syncthreads();
    if (t == 0) {
        int r = 0;
#pragma unroll
        for (int i = 0; i < 4; ++i) { int x = wsum[i]; wsum[i] = r; r += x; }
    }
    __syncthreads();
    int run = bsums[blockIdx.x] + wsum[w] + (v - s);
#pragma unroll
    for (int k = 0; k < 16; ++k) {
        int idx = base + k;
        if (idx < N) {
            offsets[idx] = run;
            cursor[idx]  = run;
            dinv[idx] = rsqrtf((float)(loc[k] + 1));   // +1 = self-loop
            run += loc[k];
        }
    }
}

// ---------------- CSR fill (counting sort by dst) ----------------
__global__ void fill_csr_kernel(const int* __restrict__ src, const int* __restrict__ dst,
                                int* __restrict__ cursor, int* __restrict__ csr_src, int E) {
    int e = blockIdx.x * blockDim.x + threadIdx.x;
    if (e >= E) return;
    int pos = atomicAdd(&cursor[dst[e]], 1);
    csr_src[pos] = src[e];
}

// ---------------- convert f32 -> bf16 (vectorized x4) ----------------
__global__ void cvt_f32_bf16_kernel(const float* __restrict__ in,
                                    __hip_bfloat16* __restrict__ out, int n4) {
    int i = blockIdx.x * blockDim.x + threadIdx.x;
    if (i >= n4) return;
    float4 v = reinterpret_cast<const float4*>(in)[i];
    __hip_bfloat16 b0 = __float2bfloat16(v.x);
    __hip_bfloat16 b1 = __float2bfloat16(v.y);
    __hip_bfloat16 b2 = __float2bfloat16(v.z);
    __hip_bfloat16 b3 = __float2bfloat16(v.w);
    ushort4 o;
    o.x = __builtin_bit_cast(unsigned short, b0);
    o.y = __builtin_bit_cast(unsigned short, b1);
    o.z = __builtin_bit_cast(unsigned short, b2);
    o.w = __builtin_bit_cast(unsigned short, b3);
    reinterpret_cast<ushort4*>(out)[i] = o;
}

// ---------------- convert all weight matrices, pad decoder to 48 rows ----------------
__global__ void cvt_weights_kernel(const float* __restrict__ encW, const float* __restrict__ W1,
                                   const float* __restrict__ W2,   const float* __restrict__ decW,
                                   __hip_bfloat16* __restrict__ encWb, __hip_bfloat16* __restrict__ W1b,
                                   __hip_bfloat16* __restrict__ W2b,   __hip_bfloat16* __restrict__ decWb) {
    int i = blockIdx.x * blockDim.x + threadIdx.x;
    if (i < 16384)      encWb[i]        = __float2bfloat16(encW[i]);
    else if (i < 32768) W1b[i - 16384]  = __float2bfloat16(W1[i - 16384]);
    else if (i < 49152) W2b[i - 32768]  = __float2bfloat16(W2[i - 32768]);
    else if (i < 49152 + 48 * 128) {
        int j = i - 49152;
        float v = (j < 40 * 128) ? decW[j] : 0.f;
        decWb[j] = __float2bfloat16(v);
    }
}

// ---------------- GEMM: out[M x ncols] = A[M x 128] @ W[ncols x 128]^T (+bias) ----------------
template<int NCT, bool OUT_F32>
__global__ __launch_bounds__(256) void gemm_bf16_k128(const __hip_bfloat16* __restrict__ A,
                                                      const __hip_bfloat16* __restrict__ W,
                                                      const float* __restrict__ bias,
                                                      void* __restrict__ out,
                                                      int M, int ldout, int ncols) {
    int lane = threadIdx.x & 63;
    int wave = threadIdx.x >> 6;
    int row0 = blockIdx.x * 64 + wave * 16;

    int arow = row0 + (lane & 15);
    if (arow >= M) arow = M - 1;
    int kgrp = lane >> 4;

    const bf16x8* Arow = reinterpret_cast<const bf16x8*>(A + (size_t)arow * 128);
    bf16x8 afrag[4];
#pragma unroll
    for (int c = 0; c < 4; ++c) afrag[c] = Arow[4 * c + kgrp];

    f32x4 acc[NCT];
#pragma unroll
    for (int t = 0; t < NCT; ++t) acc[t] = {0.f, 0.f, 0.f, 0.f};

#pragma unroll
    for (int c = 0; c < 4; ++c) {
#pragma unroll
        for (int t = 0; t < NCT; ++t) {
            int wrow = t * 16 + (lane & 15);
            bf16x8 bfrag = reinterpret_cast<const bf16x8*>(W + (size_t)wrow * 128)[4 * c + kgrp];
            acc[t] = __builtin_amdgcn_mfma_f32_16x16x32_bf16(afrag[c], bfrag, acc[t], 0, 0, 0);
        }
    }

    int rbase = row0 + kgrp * 4;
#pragma unroll
    for (int t = 0; t < NCT; ++t) {
#pragma unroll
        for (int i = 0; i < 4; ++i) {
            int r = rbase + i;
            int cidx = t * 16 + (lane & 15);
            if (r < M && cidx < ncols) {
                float v = acc[t][i];
                if (bias) v += bias[cidx];
                if (OUT_F32)
                    ((float*)out)[(size_t)r * ldout + cidx] = v;
                else
                    ((__hip_bfloat16*)out)[(size_t)r * ldout + cidx] = __float2bfloat16(v);
            }
        }
    }
}

// ---------------- aggregation ----------------
__global__ __launch_bounds__(256) void agg_kernel(const __hip_bfloat16* __restrict__ h,
                                                  const int* __restrict__ csr_src,
                                                  const int* __restrict__ offsets,
                                                  const float* __restrict__ dinv,
                                                  const float* __restrict__ bias,
                                                  __hip_bfloat16* __restrict__ out, int N) {
    int wid  = (blockIdx.x * blockDim.x + threadIdx.x) >> 6;
    int lane = threadIdx.x & 63;
    if (wid >= N) return;
    int d = wid;
    int bc = lane * 2;

    float dd = dinv[d];
    __hip_bfloat162 hv = *reinterpret_cast<const __hip_bfloat162*>(&h[(size_t)d * 128 + bc]);
    float2 hf = __bfloat1622float2(hv);
    float ax = dd * hf.x, ay = dd * hf.y;

    int j0 = offsets[d], j1 = offsets[d + 1];
    int j = j0;
    for (; j + 1 < j1; j += 2) {
        int s0 = csr_src[j], s1 = csr_src[j + 1];
        float w0 = dinv[s0], w1 = dinv[s1];
        __hip_bfloat162 v0 = *reinterpret_cast<const __hip_bfloat162*>(&h[(size_t)s0 * 128 + bc]);
        __hip_bfloat162 v1 = *reinterpret_cast<const __hip_bfloat162*>(&h[(size_t)s1 * 128 + bc]);
        float2 f0 = __bfloat1622float2(v0);
        float2 f1 = __bfloat1622float2(v1);
        ax += w0 * f0.x + w1 * f1.x;
        ay += w0 * f0.y + w1 * f1.y;
    }
    if (j < j1) {
        int s0 = csr_src[j];
        float w0 = dinv[s0];
        __hip_bfloat162 v0 = *reinterpret_cast<const __hip_bfloat162*>(&h[(size_t)s0 * 128 + bc]);
        float2 f0 = __bfloat1622float2(v0);
        ax += w0 * f0.x;
        ay += w0 * f0.y;
    }

    float2 bb = *reinterpret_cast<const float2*>(&bias[bc]);
    float ox = fmaxf(dd * ax + bb.x, 0.f);
    float oy = fmaxf(dd * ay + bb.y, 0.f);
    out[(size_t)d * 128 + bc]     = __float2bfloat16(ox);
    out[(size_t)d * 128 + bc + 1] = __float2bfloat16(oy);
}

// ---------------- log_softmax over 40 cols; one wave per row ----------------
__global__ __launch_bounds__(256) void logsoftmax_kernel(const float* __restrict__ logits,
                                                         float* __restrict__ out, int N) {
    int wid  = (blockIdx.x * blockDim.x + threadIdx.x) >> 6;
    int lane = threadIdx.x & 63;
    if (wid >= N) return;
    float v = (lane < 40) ? logits[(size_t)wid * 40 + lane] : -INFINITY;
    float m = v;
#pragma unroll
    for (int o = 32; o; o >>= 1) m = fmaxf(m, __shfl_xor(m, o));
    float e = (lane < 40) ? __expf(v - m) : 0.f;
    float s = e;
#pragma unroll
    for (int o = 32; o; o >>= 1) s += __shfl_xor(s, o);
    float lse = __logf(s);
    if (lane < 40) out[(size_t)wid * 40 + lane] = v - m - lse;
}

extern "C" void kernel_launch(void* const* d_in, const int* in_sizes, int n_in,
                              void* d_out, int out_size, void* d_ws, size_t ws_size,
                              hipStream_t stream) {
    const float* X    = (const float*)d_in[0];
    const int*   ei   = (const int*)d_in[1];
    const float* encW = (const float*)d_in[2];
    const float* encb = (const float*)d_in[3];
    const float* W1   = (const float*)d_in[4];
    const float* b1   = (const float*)d_in[5];
    const float* W2   = (const float*)d_in[6];
    const float* b2   = (const float*)d_in[7];
    const float* decW = (const float*)d_in[8];
    const float* decb = (const float*)d_in[9];

    const int N = in_sizes[0] / 128;
    const int E = in_sizes[1] / 2;
    const int* src = ei;
    const int* dst = ei + E;

    uint8_t* p = (uint8_t*)d_ws;
    auto carve = [&](size_t bytes) -> void* {
        uint8_t* r = p;
        p += (bytes + 255) & ~(size_t)255;
        return (void*)r;
    };
    int*   deg_cnt = (int*)carve((size_t)N * 4);
    int*   offsets = (int*)carve((size_t)(N + 1) * 4);
    int*   cursor  = (int*)carve((size_t)N * 4);
    float* dinv    = (float*)carve((size_t)N * 4);
    int*   bsums   = (int*)carve(1024 * 4);
    int*   csr_src = (int*)carve((size_t)E * 4);
    __hip_bfloat16* encWb = (__hip_bfloat16*)carve(16384 * 2);
    __hip_bfloat16* W1b   = (__hip_bfloat16*)carve(16384 * 2);
    __hip_bfloat16* W2b   = (__hip_bfloat16*)carve(16384 * 2);
    __hip_bfloat16* decWb = (__hip_bfloat16*)carve(48 * 128 * 2);
    __hip_bfloat16* xb    = (__hip_bfloat16*)carve((size_t)N * 128 * 2);
    __hip_bfloat16* hb    = (__hip_bfloat16*)carve((size_t)N * 128 * 2);
    float* logits = (float*)hb;

    // --- graph structure ---
    hipMemsetAsync(deg_cnt, 0, (size_t)N * 4, stream);
    count_deg_kernel<<<(E + 255) / 256, 256, 0, stream>>>(dst, deg_cnt, E);
    int nb = (N + SCAN_ELEMS - 1) / SCAN_ELEMS;   // 25 for N=100k
    scan_phaseA<<<nb, 256, 0, stream>>>(deg_cnt, bsums, N);
    scan_phaseB<<<1, 64, 0, stream>>>(bsums, nb, &offsets[N], E);
    scan_phaseC<<<nb, 256, 0, stream>>>(deg_cnt, bsums, offsets, cursor, dinv, N);
    fill_csr_kernel<<<(E + 255) / 256, 256, 0, stream>>>(src, dst, cursor, csr_src, E);

    // --- dtype conversions ---
    cvt_weights_kernel<<<(49152 + 48 * 128 + 255) / 256, 256, 0, stream>>>(
        encW, W1, W2, decW, encWb, W1b, W2b, decWb);
    int n4 = N * 128 / 4;
    cvt_f32_bf16_kernel<<<(n4 + 255) / 256, 256, 0, stream>>>(X, hb, n4);

    int gblocks = (N + 63) / 64;
    gemm_bf16_k128<8, false><<<gblocks, 256, 0, stream>>>(hb, encWb, encb, xb, N, 128, 128);
    gemm_bf16_k128<8, false><<<gblocks, 256, 0, stream>>>(xb, W1b, nullptr, hb, N, 128, 128);
    agg_kernel<<<(N + 3) / 4, 256, 0, stream>>>(hb, csr_src, offsets, dinv, b1, xb, N);
    gemm_bf16_k128<8, false><<<gblocks, 256, 0, stream>>>(xb, W2b, nullptr, hb, N, 128, 128);
    agg_kernel<<<(N + 3) / 4, 256, 0, stream>>>(hb, csr_src, offsets, dinv, b2, xb, N);
    gemm_bf16_k128<3, true><<<gblocks, 256, 0, stream>>>(xb, decWb, decb, logits, N, 40, 40);
    logsoftmax_kernel<<<(N + 3) / 4, 256, 0, stream>>>(logits, (float*)d_out, N);
}

// Round 3
// 412.546 us; speedup vs baseline: 2.0113x; 1.3715x over previous
//
#include <hip/hip_runtime.h>
#include <hip/hip_bf16.h>
#include <cstdint>

typedef __bf16 bf16x8 __attribute__((ext_vector_type(8)));
typedef float  f32x4  __attribute__((ext_vector_type(4)));

// ================= graph build: two-level counting sort =================
// bucket = dst >> SHIFT (782 buckets for N=100k, <=128 nodes each)

// ---- pass 1: bucket histogram (LDS-staged) ----
__global__ __launch_bounds__(256) void bucket_hist_kernel(const int* __restrict__ dst,
                                                          int* __restrict__ bhist,
                                                          int E, int NBK, int shift) {
    __shared__ int lh[1024];
    int t = threadIdx.x;
    for (int i = t; i < 1024; i += 256) lh[i] = 0;
    __syncthreads();
#pragma unroll
    for (int v = 0; v < 4; ++v) {
        int idx = blockIdx.x * 4096 + (v * 256 + t) * 4;
        if (idx + 3 < E) {
            int4 d = *reinterpret_cast<const int4*>(&dst[idx]);
            atomicAdd(&lh[d.x >> shift], 1);
            atomicAdd(&lh[d.y >> shift], 1);
            atomicAdd(&lh[d.z >> shift], 1);
            atomicAdd(&lh[d.w >> shift], 1);
        } else {
            for (int k = 0; k < 4; ++k)
                if (idx + k < E) atomicAdd(&lh[dst[idx + k] >> shift], 1);
        }
    }
    __syncthreads();
    for (int i = t; i < NBK; i += 256)
        if (lh[i]) atomicAdd(&bhist[i], lh[i]);
}

// ---- pass 2: scan bucket histogram (1 block) ----
__global__ __launch_bounds__(256) void bucket_scan_kernel(const int* __restrict__ bhist,
                                                          int* __restrict__ bbase,
                                                          int* __restrict__ bcur,
                                                          int NBK, int* __restrict__ offsetsN, int E) {
    int t = threadIdx.x;
    int v0[4]; int s = 0;
#pragma unroll
    for (int k = 0; k < 4; ++k) { int i = t * 4 + k; v0[k] = (i < NBK) ? bhist[i] : 0; s += v0[k]; }
    int lane = t & 63, w = t >> 6;
    int v = s;
#pragma unroll
    for (int o = 1; o < 64; o <<= 1) { int u = __shfl_up(v, o); if (lane >= o) v += u; }
    __shared__ int ws[4];
    if (lane == 63) ws[w] = v;
    __syncthreads();
    if (t == 0) { int r = 0; for (int i = 0; i < 4; ++i) { int x = ws[i]; ws[i] = r; r += x; } }
    __syncthreads();
    int run = ws[w] + (v - s);
#pragma unroll
    for (int k = 0; k < 4; ++k) {
        int i = t * 4 + k;
        if (i < NBK) { bbase[i] = run; bcur[i] = run; run += v0[k]; }
    }
    if (t == 255) bbase[NBK] = E;
    if (t == 0)   *offsetsN = E;   // offsets[N] = total edges
}

// ---- pass 3: bin edges into bucket-grouped (src,dst) pairs ----
// chunked claims: one global atomic per (block,bucket) -> contiguous runs, low write amp
__global__ __launch_bounds__(256) void bin_edges_kernel(const int* __restrict__ src,
                                                        const int* __restrict__ dst,
                                                        int* __restrict__ bcur,
                                                        uint2* __restrict__ binned,
                                                        int E, int NBK, int shift) {
    __shared__ int lh[1024];
    int t = threadIdx.x;
    for (int i = t; i < 1024; i += 256) lh[i] = 0;
    __syncthreads();
    int sv[32], dv[32], rk[32];
#pragma unroll
    for (int v = 0; v < 8; ++v) {
        int idx = blockIdx.x * 8192 + (v * 256 + t) * 4;
        if (idx + 3 < E) {
            int4 s4 = *reinterpret_cast<const int4*>(&src[idx]);
            int4 d4 = *reinterpret_cast<const int4*>(&dst[idx]);
            sv[v * 4 + 0] = s4.x; sv[v * 4 + 1] = s4.y; sv[v * 4 + 2] = s4.z; sv[v * 4 + 3] = s4.w;
            dv[v * 4 + 0] = d4.x; dv[v * 4 + 1] = d4.y; dv[v * 4 + 2] = d4.z; dv[v * 4 + 3] = d4.w;
        } else {
            for (int k = 0; k < 4; ++k) {
                sv[v * 4 + k] = (idx + k < E) ? src[idx + k] : 0;
                dv[v * 4 + k] = (idx + k < E) ? dst[idx + k] : -1;
            }
        }
    }
#pragma unroll
    for (int k = 0; k < 32; ++k)
        if (dv[k] >= 0) rk[k] = atomicAdd(&lh[dv[k] >> shift], 1);
    __syncthreads();
    for (int i = t; i < NBK; i += 256) {
        int c = lh[i];
        lh[i] = c ? atomicAdd(&bcur[i], c) : 0;
    }
    __syncthreads();
#pragma unroll
    for (int k = 0; k < 32; ++k) {
        if (dv[k] >= 0) {
            int b = dv[k] >> shift;
            binned[lh[b] + rk[k]] = make_uint2((unsigned)sv[k], (unsigned)dv[k]);
        }
    }
}

// ---- pass 4: per-bucket counting sort -> csr_src, offsets, dinv ----
__global__ __launch_bounds__(256) void bucket_build_kernel(const uint2* __restrict__ binned,
                                                           const int* __restrict__ bbase,
                                                           int* __restrict__ csr_src,
                                                           int* __restrict__ offsets,
                                                           float* __restrict__ dinv,
                                                           int N, int shift) {
    int b = blockIdx.x;
    int t = threadIdx.x;
    int node0 = b << shift;
    int npb = min(1 << shift, N - node0);
    int bb = bbase[b], be = bbase[b + 1];
    __shared__ int ncnt[256], npre[256], ncur[256];
    ncnt[t] = 0;
    __syncthreads();
    for (int e = bb + t; e < be; e += 256) {
        uint2 p = binned[e];
        atomicAdd(&ncnt[p.y - node0], 1);
    }
    __syncthreads();
    int deg = (t < npb) ? ncnt[t] : 0;
    int v = deg;
    int lane = t & 63, w = t >> 6;
#pragma unroll
    for (int o = 1; o < 64; o <<= 1) { int u = __shfl_up(v, o); if (lane >= o) v += u; }
    __shared__ int ws[4];
    if (lane == 63) ws[w] = v;
    __syncthreads();
    if (t == 0) { int r = 0; for (int i = 0; i < 4; ++i) { int x = ws[i]; ws[i] = r; r += x; } }
    __syncthreads();
    int pre = bb + ws[w] + v - deg;   // exclusive prefix = csr start of this node
    npre[t] = pre; ncur[t] = 0;
    __syncthreads();
    for (int e = bb + t; e < be; e += 256) {
        uint2 p = binned[e];
        int l = p.y - node0;
        int r = atomicAdd(&ncur[l], 1);
        csr_src[npre[l] + r] = (int)p.x;
    }
    if (t < npb) {
        int node = node0 + t;
        offsets[node] = pre;
        dinv[node] = rsqrtf((float)(deg + 1));   // +1 = self-loop
    }
}

// ---------------- convert f32 -> bf16 (vectorized x4) ----------------
__global__ void cvt_f32_bf16_kernel(const float* __restrict__ in,
                                    __hip_bfloat16* __restrict__ out, int n4) {
    int i = blockIdx.x * blockDim.x + threadIdx.x;
    if (i >= n4) return;
    float4 v = reinterpret_cast<const float4*>(in)[i];
    __hip_bfloat16 b0 = __float2bfloat16(v.x);
    __hip_bfloat16 b1 = __float2bfloat16(v.y);
    __hip_bfloat16 b2 = __float2bfloat16(v.z);
    __hip_bfloat16 b3 = __float2bfloat16(v.w);
    ushort4 o;
    o.x = __builtin_bit_cast(unsigned short, b0);
    o.y = __builtin_bit_cast(unsigned short, b1);
    o.z = __builtin_bit_cast(unsigned short, b2);
    o.w = __builtin_bit_cast(unsigned short, b3);
    reinterpret_cast<ushort4*>(out)[i] = o;
}

// ---------------- convert all weight matrices, pad decoder to 48 rows ----------------
__global__ void cvt_weights_kernel(const float* __restrict__ encW, const float* __restrict__ W1,
                                   const float* __restrict__ W2,   const float* __restrict__ decW,
                                   __hip_bfloat16* __restrict__ encWb, __hip_bfloat16* __restrict__ W1b,
                                   __hip_bfloat16* __restrict__ W2b,   __hip_bfloat16* __restrict__ decWb) {
    int i = blockIdx.x * blockDim.x + threadIdx.x;
    if (i < 16384)      encWb[i]        = __float2bfloat16(encW[i]);
    else if (i < 32768) W1b[i - 16384]  = __float2bfloat16(W1[i - 16384]);
    else if (i < 49152) W2b[i - 32768]  = __float2bfloat16(W2[i - 32768]);
    else if (i < 49152 + 48 * 128) {
        int j = i - 49152;
        float v = (j < 40 * 128) ? decW[j] : 0.f;
        decWb[j] = __float2bfloat16(v);
    }
}

// ---------------- GEMM: out[M x ncols] = A[M x 128] @ W[ncols x 128]^T (+bias) ----------------
template<int NCT, bool OUT_F32>
__global__ __launch_bounds__(256) void gemm_bf16_k128(const __hip_bfloat16* __restrict__ A,
                                                      const __hip_bfloat16* __restrict__ W,
                                                      const float* __restrict__ bias,
                                                      void* __restrict__ out,
                                                      int M, int ldout, int ncols) {
    int lane = threadIdx.x & 63;
    int wave = threadIdx.x >> 6;
    int row0 = blockIdx.x * 64 + wave * 16;

    int arow = row0 + (lane & 15);
    if (arow >= M) arow = M - 1;
    int kgrp = lane >> 4;

    const bf16x8* Arow = reinterpret_cast<const bf16x8*>(A + (size_t)arow * 128);
    bf16x8 afrag[4];
#pragma unroll
    for (int c = 0; c < 4; ++c) afrag[c] = Arow[4 * c + kgrp];

    f32x4 acc[NCT];
#pragma unroll
    for (int t = 0; t < NCT; ++t) acc[t] = {0.f, 0.f, 0.f, 0.f};

#pragma unroll
    for (int c = 0; c < 4; ++c) {
#pragma unroll
        for (int t = 0; t < NCT; ++t) {
            int wrow = t * 16 + (lane & 15);
            bf16x8 bfrag = reinterpret_cast<const bf16x8*>(W + (size_t)wrow * 128)[4 * c + kgrp];
            acc[t] = __builtin_amdgcn_mfma_f32_16x16x32_bf16(afrag[c], bfrag, acc[t], 0, 0, 0);
        }
    }

    int rbase = row0 + kgrp * 4;
#pragma unroll
    for (int t = 0; t < NCT; ++t) {
#pragma unroll
        for (int i = 0; i < 4; ++i) {
            int r = rbase + i;
            int cidx = t * 16 + (lane & 15);
            if (r < M && cidx < ncols) {
                float v = acc[t][i];
                if (bias) v += bias[cidx];
                if (OUT_F32)
                    ((float*)out)[(size_t)r * ldout + cidx] = v;
                else
                    ((__hip_bfloat16*)out)[(size_t)r * ldout + cidx] = __float2bfloat16(v);
            }
        }
    }
}

// ---------------- aggregation ----------------
__global__ __launch_bounds__(256) void agg_kernel(const __hip_bfloat16* __restrict__ h,
                                                  const int* __restrict__ csr_src,
                                                  const int* __restrict__ offsets,
                                                  const float* __restrict__ dinv,
                                                  const float* __restrict__ bias,
                                                  __hip_bfloat16* __restrict__ out, int N) {
    int wid  = (blockIdx.x * blockDim.x + threadIdx.x) >> 6;
    int lane = threadIdx.x & 63;
    if (wid >= N) return;
    int d = wid;
    int bc = lane * 2;

    float dd = dinv[d];
    __hip_bfloat162 hv = *reinterpret_cast<const __hip_bfloat162*>(&h[(size_t)d * 128 + bc]);
    float2 hf = __bfloat1622float2(hv);
    float ax = dd * hf.x, ay = dd * hf.y;

    int j0 = offsets[d], j1 = offsets[d + 1];
    int j = j0;
    for (; j + 1 < j1; j += 2) {
        int s0 = csr_src[j], s1 = csr_src[j + 1];
        float w0 = dinv[s0], w1 = dinv[s1];
        __hip_bfloat162 v0 = *reinterpret_cast<const __hip_bfloat162*>(&h[(size_t)s0 * 128 + bc]);
        __hip_bfloat162 v1 = *reinterpret_cast<const __hip_bfloat162*>(&h[(size_t)s1 * 128 + bc]);
        float2 f0 = __bfloat1622float2(v0);
        float2 f1 = __bfloat1622float2(v1);
        ax += w0 * f0.x + w1 * f1.x;
        ay += w0 * f0.y + w1 * f1.y;
    }
    if (j < j1) {
        int s0 = csr_src[j];
        float w0 = dinv[s0];
        __hip_bfloat162 v0 = *reinterpret_cast<const __hip_bfloat162*>(&h[(size_t)s0 * 128 + bc]);
        float2 f0 = __bfloat1622float2(v0);
        ax += w0 * f0.x;
        ay += w0 * f0.y;
    }

    float2 bb = *reinterpret_cast<const float2*>(&bias[bc]);
    float ox = fmaxf(dd * ax + bb.x, 0.f);
    float oy = fmaxf(dd * ay + bb.y, 0.f);
    out[(size_t)d * 128 + bc]     = __float2bfloat16(ox);
    out[(size_t)d * 128 + bc + 1] = __float2bfloat16(oy);
}

// ---------------- log_softmax over 40 cols; one wave per row ----------------
__global__ __launch_bounds__(256) void logsoftmax_kernel(const float* __restrict__ logits,
                                                         float* __restrict__ out, int N) {
    int wid  = (blockIdx.x * blockDim.x + threadIdx.x) >> 6;
    int lane = threadIdx.x & 63;
    if (wid >= N) return;
    float v = (lane < 40) ? logits[(size_t)wid * 40 + lane] : -INFINITY;
    float m = v;
#pragma unroll
    for (int o = 32; o; o >>= 1) m = fmaxf(m, __shfl_xor(m, o));
    float e = (lane < 40) ? __expf(v - m) : 0.f;
    float s = e;
#pragma unroll
    for (int o = 32; o; o >>= 1) s += __shfl_xor(s, o);
    float lse = __logf(s);
    if (lane < 40) out[(size_t)wid * 40 + lane] = v - m - lse;
}

extern "C" void kernel_launch(void* const* d_in, const int* in_sizes, int n_in,
                              void* d_out, int out_size, void* d_ws, size_t ws_size,
                              hipStream_t stream) {
    const float* X    = (const float*)d_in[0];
    const int*   ei   = (const int*)d_in[1];
    const float* encW = (const float*)d_in[2];
    const float* encb = (const float*)d_in[3];
    const float* W1   = (const float*)d_in[4];
    const float* b1   = (const float*)d_in[5];
    const float* W2   = (const float*)d_in[6];
    const float* b2   = (const float*)d_in[7];
    const float* decW = (const float*)d_in[8];
    const float* decb = (const float*)d_in[9];

    const int N = in_sizes[0] / 128;
    const int E = in_sizes[1] / 2;
    const int* src = ei;
    const int* dst = ei + E;

    int shift = 7;
    while ((((N - 1) >> shift) + 1) > 1024) ++shift;
    const int NBK = ((N - 1) >> shift) + 1;

    uint8_t* p = (uint8_t*)d_ws;
    auto carve = [&](size_t bytes) -> void* {
        uint8_t* r = p;
        p += (bytes + 255) & ~(size_t)255;
        return (void*)r;
    };
    int*   offsets = (int*)carve((size_t)(N + 1) * 4);
    float* dinv    = (float*)carve((size_t)N * 4);
    int*   bhist   = (int*)carve(1025 * 4);
    int*   bbase   = (int*)carve(1025 * 4);
    int*   bcur    = (int*)carve(1024 * 4);
    int*   csr_src = (int*)carve((size_t)E * 4);
    __hip_bfloat16* encWb = (__hip_bfloat16*)carve(16384 * 2);
    __hip_bfloat16* W1b   = (__hip_bfloat16*)carve(16384 * 2);
    __hip_bfloat16* W2b   = (__hip_bfloat16*)carve(16384 * 2);
    __hip_bfloat16* decWb = (__hip_bfloat16*)carve(48 * 128 * 2);
    __hip_bfloat16* xb    = (__hip_bfloat16*)carve((size_t)N * 128 * 2);
    __hip_bfloat16* hb    = (__hip_bfloat16*)carve((size_t)N * 128 * 2);
    float* logits = (float*)hb;                 // hb free by decoder time
    uint2* binned = (uint2*)xb;                 // binned (12.8MB) dead before xb written

    // --- graph structure ---
    hipMemsetAsync(bhist, 0, (size_t)NBK * 4, stream);
    bucket_hist_kernel<<<(E + 4095) / 4096, 256, 0, stream>>>(dst, bhist, E, NBK, shift);
    bucket_scan_kernel<<<1, 256, 0, stream>>>(bhist, bbase, bcur, NBK, &offsets[N], E);
    bin_edges_kernel<<<(E + 8191) / 8192, 256, 0, stream>>>(src, dst, bcur, binned, E, NBK, shift);
    bucket_build_kernel<<<NBK, 256, 0, stream>>>(binned, bbase, csr_src, offsets, dinv, N, shift);

    // --- dtype conversions ---
    cvt_weights_kernel<<<(49152 + 48 * 128 + 255) / 256, 256, 0, stream>>>(
        encW, W1, W2, decW, encWb, W1b, W2b, decWb);
    int n4 = N * 128 / 4;
    cvt_f32_bf16_kernel<<<(n4 + 255) / 256, 256, 0, stream>>>(X, hb, n4);

    int gblocks = (N + 63) / 64;
    gemm_bf16_k128<8, false><<<gblocks, 256, 0, stream>>>(hb, encWb, encb, xb, N, 128, 128);
    gemm_bf16_k128<8, false><<<gblocks, 256, 0, stream>>>(xb, W1b, nullptr, hb, N, 128, 128);
    agg_kernel<<<(N + 3) / 4, 256, 0, stream>>>(hb, csr_src, offsets, dinv, b1, xb, N);
    gemm_bf16_k128<8, false><<<gblocks, 256, 0, stream>>>(xb, W2b, nullptr, hb, N, 128, 128);
    agg_kernel<<<(N + 3) / 4, 256, 0, stream>>>(hb, csr_src, offsets, dinv, b2, xb, N);
    gemm_bf16_k128<3, true><<<gblocks, 256, 0, stream>>>(xb, decWb, decb, logits, N, 40, 40);
    logsoftmax_kernel<<<(N + 3) / 4, 256, 0, stream>>>(logits, (float*)d_out, N);
}

// Round 4
// 345.212 us; speedup vs baseline: 2.4036x; 1.1951x over previous
//
#include <hip/hip_runtime.h>
#include <hip/hip_bf16.h>
#include <cstdint>

typedef __bf16 bf16x8 __attribute__((ext_vector_type(8)));
typedef float  f32x4  __attribute__((ext_vector_type(4)));

// ================= graph build: two-level counting sort =================

// ---- pass 1: bucket histogram (LDS-staged) ----
__global__ __launch_bounds__(256) void bucket_hist_kernel(const int* __restrict__ dst,
                                                          int* __restrict__ bhist,
                                                          int E, int NBK, int shift) {
    __shared__ int lh[1024];
    int t = threadIdx.x;
    for (int i = t; i < 1024; i += 256) lh[i] = 0;
    __syncthreads();
#pragma unroll
    for (int v = 0; v < 4; ++v) {
        int idx = blockIdx.x * 4096 + (v * 256 + t) * 4;
        if (idx + 3 < E) {
            int4 d = *reinterpret_cast<const int4*>(&dst[idx]);
            atomicAdd(&lh[d.x >> shift], 1);
            atomicAdd(&lh[d.y >> shift], 1);
            atomicAdd(&lh[d.z >> shift], 1);
            atomicAdd(&lh[d.w >> shift], 1);
        } else {
            for (int k = 0; k < 4; ++k)
                if (idx + k < E) atomicAdd(&lh[dst[idx + k] >> shift], 1);
        }
    }
    __syncthreads();
    for (int i = t; i < NBK; i += 256)
        if (lh[i]) atomicAdd(&bhist[i], lh[i]);
}

// ---- pass 2: scan bucket histogram (1 block) ----
__global__ __launch_bounds__(256) void bucket_scan_kernel(const int* __restrict__ bhist,
                                                          int* __restrict__ bbase,
                                                          int* __restrict__ bcur,
                                                          int NBK, int* __restrict__ offsetsN, int E) {
    int t = threadIdx.x;
    int v0[4]; int s = 0;
#pragma unroll
    for (int k = 0; k < 4; ++k) { int i = t * 4 + k; v0[k] = (i < NBK) ? bhist[i] : 0; s += v0[k]; }
    int lane = t & 63, w = t >> 6;
    int v = s;
#pragma unroll
    for (int o = 1; o < 64; o <<= 1) { int u = __shfl_up(v, o); if (lane >= o) v += u; }
    __shared__ int ws[4];
    if (lane == 63) ws[w] = v;
    __syncthreads();
    if (t == 0) { int r = 0; for (int i = 0; i < 4; ++i) { int x = ws[i]; ws[i] = r; r += x; } }
    __syncthreads();
    int run = ws[w] + (v - s);
#pragma unroll
    for (int k = 0; k < 4; ++k) {
        int i = t * 4 + k;
        if (i < NBK) { bbase[i] = run; bcur[i] = run; run += v0[k]; }
    }
    if (t == 255) bbase[NBK] = E;
    if (t == 0)   *offsetsN = E;
}

// ---- pass 3: bin edges into bucket-grouped (src,dst) pairs ----
__global__ __launch_bounds__(256) void bin_edges_kernel(const int* __restrict__ src,
                                                        const int* __restrict__ dst,
                                                        int* __restrict__ bcur,
                                                        uint2* __restrict__ binned,
                                                        int E, int NBK, int shift) {
    __shared__ int lh[1024];
    int t = threadIdx.x;
    for (int i = t; i < 1024; i += 256) lh[i] = 0;
    __syncthreads();
    int sv[32], dv[32], rk[32];
#pragma unroll
    for (int v = 0; v < 8; ++v) {
        int idx = blockIdx.x * 8192 + (v * 256 + t) * 4;
        if (idx + 3 < E) {
            int4 s4 = *reinterpret_cast<const int4*>(&src[idx]);
            int4 d4 = *reinterpret_cast<const int4*>(&dst[idx]);
            sv[v * 4 + 0] = s4.x; sv[v * 4 + 1] = s4.y; sv[v * 4 + 2] = s4.z; sv[v * 4 + 3] = s4.w;
            dv[v * 4 + 0] = d4.x; dv[v * 4 + 1] = d4.y; dv[v * 4 + 2] = d4.z; dv[v * 4 + 3] = d4.w;
        } else {
            for (int k = 0; k < 4; ++k) {
                sv[v * 4 + k] = (idx + k < E) ? src[idx + k] : 0;
                dv[v * 4 + k] = (idx + k < E) ? dst[idx + k] : -1;
            }
        }
    }
#pragma unroll
    for (int k = 0; k < 32; ++k)
        if (dv[k] >= 0) rk[k] = atomicAdd(&lh[dv[k] >> shift], 1);
    __syncthreads();
    for (int i = t; i < NBK; i += 256) {
        int c = lh[i];
        lh[i] = c ? atomicAdd(&bcur[i], c) : 0;
    }
    __syncthreads();
#pragma unroll
    for (int k = 0; k < 32; ++k) {
        if (dv[k] >= 0) {
            int b = dv[k] >> shift;
            binned[lh[b] + rk[k]] = make_uint2((unsigned)sv[k], (unsigned)dv[k]);
        }
    }
}

// ---- pass 4: per-bucket counting sort -> csr_src, offsets, dinv ----
__global__ __launch_bounds__(256) void bucket_build_kernel(const uint2* __restrict__ binned,
                                                           const int* __restrict__ bbase,
                                                           int* __restrict__ csr_src,
                                                           int* __restrict__ offsets,
                                                           float* __restrict__ dinv,
                                                           int N, int shift) {
    int b = blockIdx.x;
    int t = threadIdx.x;
    int node0 = b << shift;
    int npb = min(1 << shift, N - node0);
    int bb = bbase[b], be = bbase[b + 1];
    __shared__ int ncnt[256], npre[256], ncur[256];
    ncnt[t] = 0;
    __syncthreads();
    for (int e = bb + t; e < be; e += 256) {
        uint2 p = binned[e];
        atomicAdd(&ncnt[p.y - node0], 1);
    }
    __syncthreads();
    int deg = (t < npb) ? ncnt[t] : 0;
    int v = deg;
    int lane = t & 63, w = t >> 6;
#pragma unroll
    for (int o = 1; o < 64; o <<= 1) { int u = __shfl_up(v, o); if (lane >= o) v += u; }
    __shared__ int ws[4];
    if (lane == 63) ws[w] = v;
    __syncthreads();
    if (t == 0) { int r = 0; for (int i = 0; i < 4; ++i) { int x = ws[i]; ws[i] = r; r += x; } }
    __syncthreads();
    int pre = bb + ws[w] + v - deg;
    npre[t] = pre; ncur[t] = 0;
    __syncthreads();
    for (int e = bb + t; e < be; e += 256) {
        uint2 p = binned[e];
        int l = p.y - node0;
        int r = atomicAdd(&ncur[l], 1);
        csr_src[npre[l] + r] = (int)p.x;
    }
    if (t < npb) {
        int node = node0 + t;
        offsets[node] = pre;
        dinv[node] = rsqrtf((float)(deg + 1));
    }
}

// ---------------- convert f32 -> bf16 (vectorized x4) ----------------
__global__ void cvt_f32_bf16_kernel(const float* __restrict__ in,
                                    __hip_bfloat16* __restrict__ out, int n4) {
    int i = blockIdx.x * blockDim.x + threadIdx.x;
    if (i >= n4) return;
    float4 v = reinterpret_cast<const float4*>(in)[i];
    __hip_bfloat16 b0 = __float2bfloat16(v.x);
    __hip_bfloat16 b1 = __float2bfloat16(v.y);
    __hip_bfloat16 b2 = __float2bfloat16(v.z);
    __hip_bfloat16 b3 = __float2bfloat16(v.w);
    ushort4 o;
    o.x = __builtin_bit_cast(unsigned short, b0);
    o.y = __builtin_bit_cast(unsigned short, b1);
    o.z = __builtin_bit_cast(unsigned short, b2);
    o.w = __builtin_bit_cast(unsigned short, b3);
    reinterpret_cast<ushort4*>(out)[i] = o;
}

// ---------------- convert all weight matrices, pad decoder to 48 rows ----------------
__global__ void cvt_weights_kernel(const float* __restrict__ encW, const float* __restrict__ W1,
                                   const float* __restrict__ W2,   const float* __restrict__ decW,
                                   __hip_bfloat16* __restrict__ encWb, __hip_bfloat16* __restrict__ W1b,
                                   __hip_bfloat16* __restrict__ W2b,   __hip_bfloat16* __restrict__ decWb) {
    int i = blockIdx.x * blockDim.x + threadIdx.x;
    if (i < 16384)      encWb[i]        = __float2bfloat16(encW[i]);
    else if (i < 32768) W1b[i - 16384]  = __float2bfloat16(W1[i - 16384]);
    else if (i < 49152) W2b[i - 32768]  = __float2bfloat16(W2[i - 32768]);
    else if (i < 49152 + 48 * 128) {
        int j = i - 49152;
        float v = (j < 40 * 128) ? decW[j] : 0.f;
        decWb[j] = __float2bfloat16(v);
    }
}

// ---------------- GEMM: out[M x ncols] = A[M x 128] @ W[ncols x 128]^T (+bias) ----------------
template<int NCT, bool OUT_F32>
__global__ __launch_bounds__(256) void gemm_bf16_k128(const __hip_bfloat16* __restrict__ A,
                                                      const __hip_bfloat16* __restrict__ W,
                                                      const float* __restrict__ bias,
                                                      void* __restrict__ out,
                                                      int M, int ldout, int ncols) {
    int lane = threadIdx.x & 63;
    int wave = threadIdx.x >> 6;
    int row0 = blockIdx.x * 64 + wave * 16;

    int arow = row0 + (lane & 15);
    if (arow >= M) arow = M - 1;
    int kgrp = lane >> 4;

    const bf16x8* Arow = reinterpret_cast<const bf16x8*>(A + (size_t)arow * 128);
    bf16x8 afrag[4];
#pragma unroll
    for (int c = 0; c < 4; ++c) afrag[c] = Arow[4 * c + kgrp];

    f32x4 acc[NCT];
#pragma unroll
    for (int t = 0; t < NCT; ++t) acc[t] = {0.f, 0.f, 0.f, 0.f};

#pragma unroll
    for (int c = 0; c < 4; ++c) {
#pragma unroll
        for (int t = 0; t < NCT; ++t) {
            int wrow = t * 16 + (lane & 15);
            bf16x8 bfrag = reinterpret_cast<const bf16x8*>(W + (size_t)wrow * 128)[4 * c + kgrp];
            acc[t] = __builtin_amdgcn_mfma_f32_16x16x32_bf16(afrag[c], bfrag, acc[t], 0, 0, 0);
        }
    }

    int rbase = row0 + kgrp * 4;
#pragma unroll
    for (int t = 0; t < NCT; ++t) {
#pragma unroll
        for (int i = 0; i < 4; ++i) {
            int r = rbase + i;
            int cidx = t * 16 + (lane & 15);
            if (r < M && cidx < ncols) {
                float v = acc[t][i];
                if (bias) v += bias[cidx];
                if (OUT_F32)
                    ((float*)out)[(size_t)r * ldout + cidx] = v;
                else
                    ((__hip_bfloat16*)out)[(size_t)r * ldout + cidx] = __float2bfloat16(v);
            }
        }
    }
}

// ---------------- aggregation (MLP-optimized) ----------------
// One wave per dst node. One coalesced load grabs <=64 edge indices + dinv into
// lane registers; 4-wide unrolled loop broadcasts via __shfl (uniform lane ->
// readlane/SGPR) and issues 4 independent h-row loads per iteration.
__global__ __launch_bounds__(256) void agg_kernel(const __hip_bfloat16* __restrict__ h,
                                                  const int* __restrict__ csr_src,
                                                  const int* __restrict__ offsets,
                                                  const float* __restrict__ dinv,
                                                  const float* __restrict__ bias,
                                                  __hip_bfloat16* __restrict__ out, int N) {
    int wid  = (blockIdx.x * blockDim.x + threadIdx.x) >> 6;
    int lane = threadIdx.x & 63;
    if (wid >= N) return;
    int d = wid;
    int bc = lane * 2;

    float dd = dinv[d];
    __hip_bfloat162 hv = *reinterpret_cast<const __hip_bfloat162*>(&h[(size_t)d * 128 + bc]);
    float2 hf = __bfloat1622float2(hv);
    float a0x = dd * hf.x, a0y = dd * hf.y;
    float a1x = 0.f, a1y = 0.f, a2x = 0.f, a2y = 0.f, a3x = 0.f, a3y = 0.f;

    int j0 = offsets[d], j1 = offsets[d + 1];
    for (int base = j0; base < j1; base += 64) {
        int cnt = min(64, j1 - base);
        bool valid = (base + lane) < j1;
        int   idx = valid ? csr_src[base + lane] : 0;   // one coalesced load: 64 edges
        float w   = valid ? dinv[idx] : 0.f;            // gather over 400KB (L2-hot)

        int e = 0;
        for (; e + 3 < cnt; e += 4) {
            int   s0 = __shfl(idx, e + 0), s1 = __shfl(idx, e + 1);
            int   s2 = __shfl(idx, e + 2), s3 = __shfl(idx, e + 3);
            float w0 = __shfl(w, e + 0), w1 = __shfl(w, e + 1);
            float w2 = __shfl(w, e + 2), w3 = __shfl(w, e + 3);
            float2 f0 = __bfloat1622float2(*reinterpret_cast<const __hip_bfloat162*>(&h[(size_t)s0 * 128 + bc]));
            float2 f1 = __bfloat1622float2(*reinterpret_cast<const __hip_bfloat162*>(&h[(size_t)s1 * 128 + bc]));
            float2 f2 = __bfloat1622float2(*reinterpret_cast<const __hip_bfloat162*>(&h[(size_t)s2 * 128 + bc]));
            float2 f3 = __bfloat1622float2(*reinterpret_cast<const __hip_bfloat162*>(&h[(size_t)s3 * 128 + bc]));
            a0x += w0 * f0.x; a0y += w0 * f0.y;
            a1x += w1 * f1.x; a1y += w1 * f1.y;
            a2x += w2 * f2.x; a2y += w2 * f2.y;
            a3x += w3 * f3.x; a3y += w3 * f3.y;
        }
        for (; e < cnt; ++e) {
            int   s0 = __shfl(idx, e);
            float w0 = __shfl(w, e);
            float2 f0 = __bfloat1622float2(*reinterpret_cast<const __hip_bfloat162*>(&h[(size_t)s0 * 128 + bc]));
            a0x += w0 * f0.x; a0y += w0 * f0.y;
        }
    }

    float ax = (a0x + a1x) + (a2x + a3x);
    float ay = (a0y + a1y) + (a2y + a3y);
    float2 bb = *reinterpret_cast<const float2*>(&bias[bc]);
    float ox = fmaxf(dd * ax + bb.x, 0.f);
    float oy = fmaxf(dd * ay + bb.y, 0.f);
    out[(size_t)d * 128 + bc]     = __float2bfloat16(ox);
    out[(size_t)d * 128 + bc + 1] = __float2bfloat16(oy);
}

// ---------------- log_softmax over 40 cols; one wave per row ----------------
__global__ __launch_bounds__(256) void logsoftmax_kernel(const float* __restrict__ logits,
                                                         float* __restrict__ out, int N) {
    int wid  = (blockIdx.x * blockDim.x + threadIdx.x) >> 6;
    int lane = threadIdx.x & 63;
    if (wid >= N) return;
    float v = (lane < 40) ? logits[(size_t)wid * 40 + lane] : -INFINITY;
    float m = v;
#pragma unroll
    for (int o = 32; o; o >>= 1) m = fmaxf(m, __shfl_xor(m, o));
    float e = (lane < 40) ? __expf(v - m) : 0.f;
    float s = e;
#pragma unroll
    for (int o = 32; o; o >>= 1) s += __shfl_xor(s, o);
    float lse = __logf(s);
    if (lane < 40) out[(size_t)wid * 40 + lane] = v - m - lse;
}

extern "C" void kernel_launch(void* const* d_in, const int* in_sizes, int n_in,
                              void* d_out, int out_size, void* d_ws, size_t ws_size,
                              hipStream_t stream) {
    const float* X    = (const float*)d_in[0];
    const int*   ei   = (const int*)d_in[1];
    const float* encW = (const float*)d_in[2];
    const float* encb = (const float*)d_in[3];
    const float* W1   = (const float*)d_in[4];
    const float* b1   = (const float*)d_in[5];
    const float* W2   = (const float*)d_in[6];
    const float* b2   = (const float*)d_in[7];
    const float* decW = (const float*)d_in[8];
    const float* decb = (const float*)d_in[9];

    const int N = in_sizes[0] / 128;
    const int E = in_sizes[1] / 2;
    const int* src = ei;
    const int* dst = ei + E;

    int shift = 7;
    while ((((N - 1) >> shift) + 1) > 1024) ++shift;
    const int NBK = ((N - 1) >> shift) + 1;

    uint8_t* p = (uint8_t*)d_ws;
    auto carve = [&](size_t bytes) -> void* {
        uint8_t* r = p;
        p += (bytes + 255) & ~(size_t)255;
        return (void*)r;
    };
    int*   offsets = (int*)carve((size_t)(N + 1) * 4);
    float* dinv    = (float*)carve((size_t)N * 4);
    int*   bhist   = (int*)carve(1025 * 4);
    int*   bbase   = (int*)carve(1025 * 4);
    int*   bcur    = (int*)carve(1024 * 4);
    int*   csr_src = (int*)carve((size_t)E * 4);
    __hip_bfloat16* encWb = (__hip_bfloat16*)carve(16384 * 2);
    __hip_bfloat16* W1b   = (__hip_bfloat16*)carve(16384 * 2);
    __hip_bfloat16* W2b   = (__hip_bfloat16*)carve(16384 * 2);
    __hip_bfloat16* decWb = (__hip_bfloat16*)carve(48 * 128 * 2);
    __hip_bfloat16* xb    = (__hip_bfloat16*)carve((size_t)N * 128 * 2);
    __hip_bfloat16* hb    = (__hip_bfloat16*)carve((size_t)N * 128 * 2);
    float* logits = (float*)hb;
    uint2* binned = (uint2*)xb;

    // --- graph structure ---
    hipMemsetAsync(bhist, 0, (size_t)NBK * 4, stream);
    bucket_hist_kernel<<<(E + 4095) / 4096, 256, 0, stream>>>(dst, bhist, E, NBK, shift);
    bucket_scan_kernel<<<1, 256, 0, stream>>>(bhist, bbase, bcur, NBK, &offsets[N], E);
    bin_edges_kernel<<<(E + 8191) / 8192, 256, 0, stream>>>(src, dst, bcur, binned, E, NBK, shift);
    bucket_build_kernel<<<NBK, 256, 0, stream>>>(binned, bbase, csr_src, offsets, dinv, N, shift);

    // --- dtype conversions ---
    cvt_weights_kernel<<<(49152 + 48 * 128 + 255) / 256, 256, 0, stream>>>(
        encW, W1, W2, decW, encWb, W1b, W2b, decWb);
    int n4 = N * 128 / 4;
    cvt_f32_bf16_kernel<<<(n4 + 255) / 256, 256, 0, stream>>>(X, hb, n4);

    int gblocks = (N + 63) / 64;
    gemm_bf16_k128<8, false><<<gblocks, 256, 0, stream>>>(hb, encWb, encb, xb, N, 128, 128);
    gemm_bf16_k128<8, false><<<gblocks, 256, 0, stream>>>(xb, W1b, nullptr, hb, N, 128, 128);
    agg_kernel<<<(N + 3) / 4, 256, 0, stream>>>(hb, csr_src, offsets, dinv, b1, xb, N);
    gemm_bf16_k128<8, false><<<gblocks, 256, 0, stream>>>(xb, W2b, nullptr, hb, N, 128, 128);
    agg_kernel<<<(N + 3) / 4, 256, 0, stream>>>(hb, csr_src, offsets, dinv, b2, xb, N);
    gemm_bf16_k128<3, true><<<gblocks, 256, 0, stream>>>(xb, decWb, decb, logits, N, 40, 40);
    logsoftmax_kernel<<<(N + 3) / 4, 256, 0, stream>>>(logits, (float*)d_out, N);
}

// Round 5
// 297.911 us; speedup vs baseline: 2.7852x; 1.1588x over previous
//
#include <hip/hip_runtime.h>
#include <hip/hip_bf16.h>
#include <cstdint>

typedef __bf16 bf16x8 __attribute__((ext_vector_type(8)));
typedef float  f32x4  __attribute__((ext_vector_type(4)));

// ================= graph build: two-level counting sort =================

__global__ __launch_bounds__(256) void bucket_hist_kernel(const int* __restrict__ dst,
                                                          int* __restrict__ bhist,
                                                          int E, int NBK, int shift) {
    __shared__ int lh[1024];
    int t = threadIdx.x;
    for (int i = t; i < 1024; i += 256) lh[i] = 0;
    __syncthreads();
#pragma unroll
    for (int v = 0; v < 4; ++v) {
        int idx = blockIdx.x * 4096 + (v * 256 + t) * 4;
        if (idx + 3 < E) {
            int4 d = *reinterpret_cast<const int4*>(&dst[idx]);
            atomicAdd(&lh[d.x >> shift], 1);
            atomicAdd(&lh[d.y >> shift], 1);
            atomicAdd(&lh[d.z >> shift], 1);
            atomicAdd(&lh[d.w >> shift], 1);
        } else {
            for (int k = 0; k < 4; ++k)
                if (idx + k < E) atomicAdd(&lh[dst[idx + k] >> shift], 1);
        }
    }
    __syncthreads();
    for (int i = t; i < NBK; i += 256)
        if (lh[i]) atomicAdd(&bhist[i], lh[i]);
}

__global__ __launch_bounds__(256) void bucket_scan_kernel(const int* __restrict__ bhist,
                                                          int* __restrict__ bbase,
                                                          int* __restrict__ bcur,
                                                          int NBK, int* __restrict__ offsetsN, int E) {
    int t = threadIdx.x;
    int v0[4]; int s = 0;
#pragma unroll
    for (int k = 0; k < 4; ++k) { int i = t * 4 + k; v0[k] = (i < NBK) ? bhist[i] : 0; s += v0[k]; }
    int lane = t & 63, w = t >> 6;
    int v = s;
#pragma unroll
    for (int o = 1; o < 64; o <<= 1) { int u = __shfl_up(v, o); if (lane >= o) v += u; }
    __shared__ int ws[4];
    if (lane == 63) ws[w] = v;
    __syncthreads();
    if (t == 0) { int r = 0; for (int i = 0; i < 4; ++i) { int x = ws[i]; ws[i] = r; r += x; } }
    __syncthreads();
    int run = ws[w] + (v - s);
#pragma unroll
    for (int k = 0; k < 4; ++k) {
        int i = t * 4 + k;
        if (i < NBK) { bbase[i] = run; bcur[i] = run; run += v0[k]; }
    }
    if (t == 255) bbase[NBK] = E;
    if (t == 0)   *offsetsN = E;
}

__global__ __launch_bounds__(256) void bin_edges_kernel(const int* __restrict__ src,
                                                        const int* __restrict__ dst,
                                                        int* __restrict__ bcur,
                                                        uint2* __restrict__ binned,
                                                        int E, int NBK, int shift) {
    __shared__ int lh[1024];
    int t = threadIdx.x;
    for (int i = t; i < 1024; i += 256) lh[i] = 0;
    __syncthreads();
    int sv[32], dv[32], rk[32];
#pragma unroll
    for (int v = 0; v < 8; ++v) {
        int idx = blockIdx.x * 8192 + (v * 256 + t) * 4;
        if (idx + 3 < E) {
            int4 s4 = *reinterpret_cast<const int4*>(&src[idx]);
            int4 d4 = *reinterpret_cast<const int4*>(&dst[idx]);
            sv[v * 4 + 0] = s4.x; sv[v * 4 + 1] = s4.y; sv[v * 4 + 2] = s4.z; sv[v * 4 + 3] = s4.w;
            dv[v * 4 + 0] = d4.x; dv[v * 4 + 1] = d4.y; dv[v * 4 + 2] = d4.z; dv[v * 4 + 3] = d4.w;
        } else {
            for (int k = 0; k < 4; ++k) {
                sv[v * 4 + k] = (idx + k < E) ? src[idx + k] : 0;
                dv[v * 4 + k] = (idx + k < E) ? dst[idx + k] : -1;
            }
        }
    }
#pragma unroll
    for (int k = 0; k < 32; ++k)
        if (dv[k] >= 0) rk[k] = atomicAdd(&lh[dv[k] >> shift], 1);
    __syncthreads();
    for (int i = t; i < NBK; i += 256) {
        int c = lh[i];
        lh[i] = c ? atomicAdd(&bcur[i], c) : 0;
    }
    __syncthreads();
#pragma unroll
    for (int k = 0; k < 32; ++k) {
        if (dv[k] >= 0) {
            int b = dv[k] >> shift;
            binned[lh[b] + rk[k]] = make_uint2((unsigned)sv[k], (unsigned)dv[k]);
        }
    }
}

__global__ __launch_bounds__(256) void bucket_build_kernel(const uint2* __restrict__ binned,
                                                           const int* __restrict__ bbase,
                                                           int* __restrict__ csr_src,
                                                           int* __restrict__ offsets,
                                                           float* __restrict__ dinv,
                                                           int N, int shift) {
    int b = blockIdx.x;
    int t = threadIdx.x;
    int node0 = b << shift;
    int npb = min(1 << shift, N - node0);
    int bb = bbase[b], be = bbase[b + 1];
    __shared__ int ncnt[256], npre[256], ncur[256];
    ncnt[t] = 0;
    __syncthreads();
    for (int e = bb + t; e < be; e += 256) {
        uint2 p = binned[e];
        atomicAdd(&ncnt[p.y - node0], 1);
    }
    __syncthreads();
    int deg = (t < npb) ? ncnt[t] : 0;
    int v = deg;
    int lane = t & 63, w = t >> 6;
#pragma unroll
    for (int o = 1; o < 64; o <<= 1) { int u = __shfl_up(v, o); if (lane >= o) v += u; }
    __shared__ int ws[4];
    if (lane == 63) ws[w] = v;
    __syncthreads();
    if (t == 0) { int r = 0; for (int i = 0; i < 4; ++i) { int x = ws[i]; ws[i] = r; r += x; } }
    __syncthreads();
    int pre = bb + ws[w] + v - deg;
    npre[t] = pre; ncur[t] = 0;
    __syncthreads();
    for (int e = bb + t; e < be; e += 256) {
        uint2 p = binned[e];
        int l = p.y - node0;
        int r = atomicAdd(&ncur[l], 1);
        csr_src[npre[l] + r] = (int)p.x;
    }
    if (t < npb) {
        int node = node0 + t;
        offsets[node] = pre;
        dinv[node] = rsqrtf((float)(deg + 1));
    }
}

// ---------------- weight conversion ----------------
__global__ void cvt_weights_kernel(const float* __restrict__ encW, const float* __restrict__ W1,
                                   const float* __restrict__ W2,   const float* __restrict__ decW,
                                   __hip_bfloat16* __restrict__ encWb, __hip_bfloat16* __restrict__ W1b,
                                   __hip_bfloat16* __restrict__ W2b,   __hip_bfloat16* __restrict__ decWb) {
    int i = blockIdx.x * blockDim.x + threadIdx.x;
    if (i < 16384)      encWb[i]        = __float2bfloat16(encW[i]);
    else if (i < 32768) W1b[i - 16384]  = __float2bfloat16(W1[i - 16384]);
    else if (i < 49152) W2b[i - 32768]  = __float2bfloat16(W2[i - 32768]);
    else if (i < 49152 + 48 * 128) {
        int j = i - 49152;
        float v = (j < 40 * 128) ? decW[j] : 0.f;
        decWb[j] = __float2bfloat16(v);
    }
}

__device__ inline bf16x8 cvt8(float4 lo, float4 hi) {
    union { unsigned short u[8]; bf16x8 v; } t;
    t.u[0] = __builtin_bit_cast(unsigned short, __float2bfloat16(lo.x));
    t.u[1] = __builtin_bit_cast(unsigned short, __float2bfloat16(lo.y));
    t.u[2] = __builtin_bit_cast(unsigned short, __float2bfloat16(lo.z));
    t.u[3] = __builtin_bit_cast(unsigned short, __float2bfloat16(lo.w));
    t.u[4] = __builtin_bit_cast(unsigned short, __float2bfloat16(hi.x));
    t.u[5] = __builtin_bit_cast(unsigned short, __float2bfloat16(hi.y));
    t.u[6] = __builtin_bit_cast(unsigned short, __float2bfloat16(hi.z));
    t.u[7] = __builtin_bit_cast(unsigned short, __float2bfloat16(hi.w));
    return t.v;
}

// ---------------- GEMM: out[M x 128] = A[M x 128] @ W[128 x 128]^T (+bias) ----------------
// 32 rows/wave (2 row-tiles share each B fragment), 128 rows/block.
// Epilogue: shfl-pack 2 bf16 -> one 4B store per even lane.
template<bool A_F32>
__global__ __launch_bounds__(256) void gemm_k128(const void* __restrict__ Ain,
                                                 const __hip_bfloat16* __restrict__ W,
                                                 const float* __restrict__ bias,
                                                 __hip_bfloat16* __restrict__ out, int M) {
    int lane = threadIdx.x & 63;
    int wave = threadIdx.x >> 6;
    int row0 = blockIdx.x * 128 + wave * 32;
    int kgrp = lane >> 4, cl = lane & 15;

    bf16x8 afrag[2][4];
#pragma unroll
    for (int rt = 0; rt < 2; ++rt) {
        int ar = row0 + rt * 16 + cl;
        if (ar >= M) ar = M - 1;
        if (A_F32) {
            const float* Ar = (const float*)Ain + (size_t)ar * 128;
#pragma unroll
            for (int c = 0; c < 4; ++c) {
                const float4* q = reinterpret_cast<const float4*>(Ar + (4 * c + kgrp) * 8);
                afrag[rt][c] = cvt8(q[0], q[1]);
            }
        } else {
            const bf16x8* Ar = reinterpret_cast<const bf16x8*>((const __hip_bfloat16*)Ain + (size_t)ar * 128);
#pragma unroll
            for (int c = 0; c < 4; ++c) afrag[rt][c] = Ar[4 * c + kgrp];
        }
    }

    f32x4 acc[2][8];
#pragma unroll
    for (int rt = 0; rt < 2; ++rt)
#pragma unroll
        for (int t = 0; t < 8; ++t) acc[rt][t] = {0.f, 0.f, 0.f, 0.f};

#pragma unroll
    for (int c = 0; c < 4; ++c) {
#pragma unroll
        for (int t = 0; t < 8; ++t) {
            bf16x8 bfrag = reinterpret_cast<const bf16x8*>(W + (size_t)(t * 16 + cl) * 128)[4 * c + kgrp];
            acc[0][t] = __builtin_amdgcn_mfma_f32_16x16x32_bf16(afrag[0][c], bfrag, acc[0][t], 0, 0, 0);
            acc[1][t] = __builtin_amdgcn_mfma_f32_16x16x32_bf16(afrag[1][c], bfrag, acc[1][t], 0, 0, 0);
        }
    }

#pragma unroll
    for (int rt = 0; rt < 2; ++rt) {
        int rbase = row0 + rt * 16 + kgrp * 4;
#pragma unroll
        for (int t = 0; t < 8; ++t) {
            int col = t * 16 + cl;
            float bv = bias ? bias[col] : 0.f;
#pragma unroll
            for (int i = 0; i < 4; ++i) {
                int r = rbase + i;
                float v = acc[rt][t][i] + bv;
                unsigned int uv = __builtin_bit_cast(unsigned short, __float2bfloat16(v));
                unsigned int pv = (unsigned int)__shfl_xor((int)uv, 1);
                if (!(lane & 1) && r < M)
                    *reinterpret_cast<unsigned int*>(out + (size_t)r * 128 + col) = (uv & 0xffffu) | (pv << 16);
            }
        }
    }
}

// ---------------- aggregation (8-wide MLP) ----------------
__global__ __launch_bounds__(256) void agg_kernel(const __hip_bfloat16* __restrict__ h,
                                                  const int* __restrict__ csr_src,
                                                  const int* __restrict__ offsets,
                                                  const float* __restrict__ dinv,
                                                  const float* __restrict__ bias,
                                                  __hip_bfloat16* __restrict__ out, int N) {
    int wid  = (blockIdx.x * blockDim.x + threadIdx.x) >> 6;
    int lane = threadIdx.x & 63;
    if (wid >= N) return;
    int d = wid;
    int bc = lane * 2;

    float dd = dinv[d];
    __hip_bfloat162 hv = *reinterpret_cast<const __hip_bfloat162*>(&h[(size_t)d * 128 + bc]);
    float2 hf = __bfloat1622float2(hv);
    float ax[8], ay[8];
    ax[0] = dd * hf.x; ay[0] = dd * hf.y;
#pragma unroll
    for (int k = 1; k < 8; ++k) { ax[k] = 0.f; ay[k] = 0.f; }

    int j0 = offsets[d], j1 = offsets[d + 1];
    for (int base = j0; base < j1; base += 64) {
        int cnt = min(64, j1 - base);
        bool valid = (base + lane) < j1;
        int   idx = valid ? csr_src[base + lane] : 0;
        float w   = valid ? dinv[idx] : 0.f;

        int e = 0;
        for (; e + 7 < cnt; e += 8) {
            int   s[8]; float wt[8];
#pragma unroll
            for (int k = 0; k < 8; ++k) { s[k] = __shfl(idx, e + k); wt[k] = __shfl(w, e + k); }
#pragma unroll
            for (int k = 0; k < 8; ++k) {
                float2 f = __bfloat1622float2(*reinterpret_cast<const __hip_bfloat162*>(&h[(size_t)s[k] * 128 + bc]));
                ax[k] += wt[k] * f.x; ay[k] += wt[k] * f.y;
            }
        }
        for (; e + 3 < cnt; e += 4) {
            int   s[4]; float wt[4];
#pragma unroll
            for (int k = 0; k < 4; ++k) { s[k] = __shfl(idx, e + k); wt[k] = __shfl(w, e + k); }
#pragma unroll
            for (int k = 0; k < 4; ++k) {
                float2 f = __bfloat1622float2(*reinterpret_cast<const __hip_bfloat162*>(&h[(size_t)s[k] * 128 + bc]));
                ax[k] += wt[k] * f.x; ay[k] += wt[k] * f.y;
            }
        }
        for (; e < cnt; ++e) {
            int   s0 = __shfl(idx, e);
            float w0 = __shfl(w, e);
            float2 f = __bfloat1622float2(*reinterpret_cast<const __hip_bfloat162*>(&h[(size_t)s0 * 128 + bc]));
            ax[0] += w0 * f.x; ay[0] += w0 * f.y;
        }
    }

    float sx = ((ax[0] + ax[1]) + (ax[2] + ax[3])) + ((ax[4] + ax[5]) + (ax[6] + ax[7]));
    float sy = ((ay[0] + ay[1]) + (ay[2] + ay[3])) + ((ay[4] + ay[5]) + (ay[6] + ay[7]));
    float2 bb = *reinterpret_cast<const float2*>(&bias[bc]);
    float ox = fmaxf(dd * sx + bb.x, 0.f);
    float oy = fmaxf(dd * sy + bb.y, 0.f);
    out[(size_t)d * 128 + bc]     = __float2bfloat16(ox);
    out[(size_t)d * 128 + bc + 1] = __float2bfloat16(oy);
}

// ---------------- fused decoder GEMM + log_softmax ----------------
// One wave per 16 rows; 48 padded cols (3 col-tiles); logits stay in registers.
__global__ __launch_bounds__(256) void dec_softmax_kernel(const __hip_bfloat16* __restrict__ A,
                                                          const __hip_bfloat16* __restrict__ Wd,
                                                          const float* __restrict__ bd,
                                                          float* __restrict__ out, int M) {
    int lane = threadIdx.x & 63;
    int wid  = (blockIdx.x * blockDim.x + threadIdx.x) >> 6;
    int row0 = wid * 16;
    if (row0 >= M) return;
    int kgrp = lane >> 4, cl = lane & 15;

    int ar = row0 + cl;
    if (ar >= M) ar = M - 1;
    const bf16x8* Ar = reinterpret_cast<const bf16x8*>(A + (size_t)ar * 128);
    bf16x8 afrag[4];
#pragma unroll
    for (int c = 0; c < 4; ++c) afrag[c] = Ar[4 * c + kgrp];

    f32x4 acc[3];
#pragma unroll
    for (int t = 0; t < 3; ++t) acc[t] = {0.f, 0.f, 0.f, 0.f};
#pragma unroll
    for (int c = 0; c < 4; ++c)
#pragma unroll
        for (int t = 0; t < 3; ++t) {
            bf16x8 bfrag = reinterpret_cast<const bf16x8*>(Wd + (size_t)(t * 16 + cl) * 128)[4 * c + kgrp];
            acc[t] = __builtin_amdgcn_mfma_f32_16x16x32_bf16(afrag[c], bfrag, acc[t], 0, 0, 0);
        }

    // logits v[t][i]: row = row0 + kgrp*4 + i, col = t*16 + cl
    float v[3][4];
#pragma unroll
    for (int t = 0; t < 3; ++t) {
        int col = t * 16 + cl;
        float bv = (col < 40) ? bd[col] : 0.f;
#pragma unroll
        for (int i = 0; i < 4; ++i)
            v[t][i] = (col < 40) ? (acc[t][i] + bv) : -INFINITY;
    }

#pragma unroll
    for (int i = 0; i < 4; ++i) {
        float m = fmaxf(fmaxf(v[0][i], v[1][i]), v[2][i]);
#pragma unroll
        for (int o = 1; o < 16; o <<= 1) m = fmaxf(m, __shfl_xor(m, o));
        float s = 0.f;
#pragma unroll
        for (int t = 0; t < 3; ++t) s += (v[t][i] > -INFINITY) ? __expf(v[t][i] - m) : 0.f;
#pragma unroll
        for (int o = 1; o < 16; o <<= 1) s += __shfl_xor(s, o);
        float lse = __logf(s);
        int r = row0 + kgrp * 4 + i;
        if (r < M) {
#pragma unroll
            for (int t = 0; t < 3; ++t) {
                int col = t * 16 + cl;
                if (col < 40) out[(size_t)r * 40 + col] = v[t][i] - m - lse;
            }
        }
    }
}

extern "C" void kernel_launch(void* const* d_in, const int* in_sizes, int n_in,
                              void* d_out, int out_size, void* d_ws, size_t ws_size,
                              hipStream_t stream) {
    const float* X    = (const float*)d_in[0];
    const int*   ei   = (const int*)d_in[1];
    const float* encW = (const float*)d_in[2];
    const float* encb = (const float*)d_in[3];
    const float* W1   = (const float*)d_in[4];
    const float* b1   = (const float*)d_in[5];
    const float* W2   = (const float*)d_in[6];
    const float* b2   = (const float*)d_in[7];
    const float* decW = (const float*)d_in[8];
    const float* decb = (const float*)d_in[9];

    const int N = in_sizes[0] / 128;
    const int E = in_sizes[1] / 2;
    const int* src = ei;
    const int* dst = ei + E;

    int shift = 7;
    while ((((N - 1) >> shift) + 1) > 1024) ++shift;
    const int NBK = ((N - 1) >> shift) + 1;

    uint8_t* p = (uint8_t*)d_ws;
    auto carve = [&](size_t bytes) -> void* {
        uint8_t* r = p;
        p += (bytes + 255) & ~(size_t)255;
        return (void*)r;
    };
    int*   offsets = (int*)carve((size_t)(N + 1) * 4);
    float* dinv    = (float*)carve((size_t)N * 4);
    int*   bhist   = (int*)carve(1025 * 4);
    int*   bbase   = (int*)carve(1025 * 4);
    int*   bcur    = (int*)carve(1024 * 4);
    int*   csr_src = (int*)carve((size_t)E * 4);
    __hip_bfloat16* encWb = (__hip_bfloat16*)carve(16384 * 2);
    __hip_bfloat16* W1b   = (__hip_bfloat16*)carve(16384 * 2);
    __hip_bfloat16* W2b   = (__hip_bfloat16*)carve(16384 * 2);
    __hip_bfloat16* decWb = (__hip_bfloat16*)carve(48 * 128 * 2);
    __hip_bfloat16* xb    = (__hip_bfloat16*)carve((size_t)N * 128 * 2);
    __hip_bfloat16* hb    = (__hip_bfloat16*)carve((size_t)N * 128 * 2);
    uint2* binned = (uint2*)xb;   // dead before xb is first written

    // --- graph structure ---
    hipMemsetAsync(bhist, 0, (size_t)NBK * 4, stream);
    bucket_hist_kernel<<<(E + 4095) / 4096, 256, 0, stream>>>(dst, bhist, E, NBK, shift);
    bucket_scan_kernel<<<1, 256, 0, stream>>>(bhist, bbase, bcur, NBK, &offsets[N], E);
    bin_edges_kernel<<<(E + 8191) / 8192, 256, 0, stream>>>(src, dst, bcur, binned, E, NBK, shift);
    bucket_build_kernel<<<NBK, 256, 0, stream>>>(binned, bbase, csr_src, offsets, dinv, N, shift);

    cvt_weights_kernel<<<(49152 + 48 * 128 + 255) / 256, 256, 0, stream>>>(
        encW, W1, W2, decW, encWb, W1b, W2b, decWb);

    int gblocks = (N + 127) / 128;
    // encoder: xb = bf16(X @ encW^T + encb)   (reads X f32 directly)
    gemm_k128<true><<<gblocks, 256, 0, stream>>>(X, encWb, encb, xb, N);
    // conv1
    gemm_k128<false><<<gblocks, 256, 0, stream>>>(xb, W1b, nullptr, hb, N);
    agg_kernel<<<(N + 3) / 4, 256, 0, stream>>>(hb, csr_src, offsets, dinv, b1, xb, N);
    // conv2
    gemm_k128<false><<<gblocks, 256, 0, stream>>>(xb, W2b, nullptr, hb, N);
    agg_kernel<<<(N + 3) / 4, 256, 0, stream>>>(hb, csr_src, offsets, dinv, b2, xb, N);
    // decoder + log_softmax fused
    dec_softmax_kernel<<<(N + 63) / 64, 256, 0, stream>>>(xb, decWb, decb, (float*)d_out, N);
}

// Round 6
// 286.752 us; speedup vs baseline: 2.8936x; 1.0389x over previous
//
#include <hip/hip_runtime.h>
#include <hip/hip_bf16.h>
#include <cstdint>

typedef __bf16 bf16x8 __attribute__((ext_vector_type(8)));
typedef float  f32x4  __attribute__((ext_vector_type(4)));

// ================= graph build: two-level counting sort =================

__global__ __launch_bounds__(256) void bucket_hist_kernel(const int* __restrict__ dst,
                                                          int* __restrict__ bhist,
                                                          int E, int NBK, int shift) {
    __shared__ int lh[1024];
    int t = threadIdx.x;
    for (int i = t; i < 1024; i += 256) lh[i] = 0;
    __syncthreads();
#pragma unroll
    for (int v = 0; v < 4; ++v) {
        int idx = blockIdx.x * 4096 + (v * 256 + t) * 4;
        if (idx + 3 < E) {
            int4 d = *reinterpret_cast<const int4*>(&dst[idx]);
            atomicAdd(&lh[d.x >> shift], 1);
            atomicAdd(&lh[d.y >> shift], 1);
            atomicAdd(&lh[d.z >> shift], 1);
            atomicAdd(&lh[d.w >> shift], 1);
        } else {
            for (int k = 0; k < 4; ++k)
                if (idx + k < E) atomicAdd(&lh[dst[idx + k] >> shift], 1);
        }
    }
    __syncthreads();
    for (int i = t; i < NBK; i += 256)
        if (lh[i]) atomicAdd(&bhist[i], lh[i]);
}

__global__ __launch_bounds__(256) void bucket_scan_kernel(const int* __restrict__ bhist,
                                                          int* __restrict__ bbase,
                                                          int* __restrict__ bcur,
                                                          int NBK, int* __restrict__ offsetsN, int E) {
    int t = threadIdx.x;
    int v0[4]; int s = 0;
#pragma unroll
    for (int k = 0; k < 4; ++k) { int i = t * 4 + k; v0[k] = (i < NBK) ? bhist[i] : 0; s += v0[k]; }
    int lane = t & 63, w = t >> 6;
    int v = s;
#pragma unroll
    for (int o = 1; o < 64; o <<= 1) { int u = __shfl_up(v, o); if (lane >= o) v += u; }
    __shared__ int ws[4];
    if (lane == 63) ws[w] = v;
    __syncthreads();
    if (t == 0) { int r = 0; for (int i = 0; i < 4; ++i) { int x = ws[i]; ws[i] = r; r += x; } }
    __syncthreads();
    int run = ws[w] + (v - s);
#pragma unroll
    for (int k = 0; k < 4; ++k) {
        int i = t * 4 + k;
        if (i < NBK) { bbase[i] = run; bcur[i] = run; run += v0[k]; }
    }
    if (t == 255) bbase[NBK] = E;
    if (t == 0)   *offsetsN = E;
}

__global__ __launch_bounds__(256) void bin_edges_kernel(const int* __restrict__ src,
                                                        const int* __restrict__ dst,
                                                        int* __restrict__ bcur,
                                                        uint2* __restrict__ binned,
                                                        int E, int NBK, int shift) {
    __shared__ int lh[1024];
    int t = threadIdx.x;
    for (int i = t; i < 1024; i += 256) lh[i] = 0;
    __syncthreads();
    int sv[32], dv[32], rk[32];
#pragma unroll
    for (int v = 0; v < 8; ++v) {
        int idx = blockIdx.x * 8192 + (v * 256 + t) * 4;
        if (idx + 3 < E) {
            int4 s4 = *reinterpret_cast<const int4*>(&src[idx]);
            int4 d4 = *reinterpret_cast<const int4*>(&dst[idx]);
            sv[v * 4 + 0] = s4.x; sv[v * 4 + 1] = s4.y; sv[v * 4 + 2] = s4.z; sv[v * 4 + 3] = s4.w;
            dv[v * 4 + 0] = d4.x; dv[v * 4 + 1] = d4.y; dv[v * 4 + 2] = d4.z; dv[v * 4 + 3] = d4.w;
        } else {
            for (int k = 0; k < 4; ++k) {
                sv[v * 4 + k] = (idx + k < E) ? src[idx + k] : 0;
                dv[v * 4 + k] = (idx + k < E) ? dst[idx + k] : -1;
            }
        }
    }
#pragma unroll
    for (int k = 0; k < 32; ++k)
        if (dv[k] >= 0) rk[k] = atomicAdd(&lh[dv[k] >> shift], 1);
    __syncthreads();
    for (int i = t; i < NBK; i += 256) {
        int c = lh[i];
        lh[i] = c ? atomicAdd(&bcur[i], c) : 0;
    }
    __syncthreads();
#pragma unroll
    for (int k = 0; k < 32; ++k) {
        if (dv[k] >= 0) {
            int b = dv[k] >> shift;
            binned[lh[b] + rk[k]] = make_uint2((unsigned)sv[k], (unsigned)dv[k]);
        }
    }
}

__global__ __launch_bounds__(256) void bucket_build_kernel(const uint2* __restrict__ binned,
                                                           const int* __restrict__ bbase,
                                                           int* __restrict__ csr_src,
                                                           int* __restrict__ offsets,
                                                           float* __restrict__ dinv,
                                                           int N, int shift) {
    int b = blockIdx.x;
    int t = threadIdx.x;
    int node0 = b << shift;
    int npb = min(1 << shift, N - node0);
    int bb = bbase[b], be = bbase[b + 1];
    __shared__ int ncnt[256], npre[256], ncur[256];
    ncnt[t] = 0;
    __syncthreads();
    for (int e = bb + t; e < be; e += 256) {
        uint2 p = binned[e];
        atomicAdd(&ncnt[p.y - node0], 1);
    }
    __syncthreads();
    int deg = (t < npb) ? ncnt[t] : 0;
    int v = deg;
    int lane = t & 63, w = t >> 6;
#pragma unroll
    for (int o = 1; o < 64; o <<= 1) { int u = __shfl_up(v, o); if (lane >= o) v += u; }
    __shared__ int ws[4];
    if (lane == 63) ws[w] = v;
    __syncthreads();
    if (t == 0) { int r = 0; for (int i = 0; i < 4; ++i) { int x = ws[i]; ws[i] = r; r += x; } }
    __syncthreads();
    int pre = bb + ws[w] + v - deg;
    npre[t] = pre; ncur[t] = 0;
    __syncthreads();
    for (int e = bb + t; e < be; e += 256) {
        uint2 p = binned[e];
        int l = p.y - node0;
        int r = atomicAdd(&ncur[l], 1);
        csr_src[npre[l] + r] = (int)p.x;
    }
    if (t < npb) {
        int node = node0 + t;
        offsets[node] = pre;
        dinv[node] = rsqrtf((float)(deg + 1));
    }
}

// ---------------- weight prep: Wf = W1@encW (f32), bf = W1@encb; cvt all to bf16 ----------------
__global__ __launch_bounds__(128) void prep_weights_kernel(const float* __restrict__ W1,
                                                           const float* __restrict__ encW,
                                                           const float* __restrict__ encb,
                                                           const float* __restrict__ W2,
                                                           const float* __restrict__ decW,
                                                           __hip_bfloat16* __restrict__ Wfb,
                                                           float* __restrict__ bff,
                                                           __hip_bfloat16* __restrict__ W2b,
                                                           __hip_bfloat16* __restrict__ decWb) {
    int i = blockIdx.x;     // 128 rows
    int j = threadIdx.x;    // 128 cols
    const float* w1r = W1 + (size_t)i * 128;
    float s0 = 0.f, s1 = 0.f, s2 = 0.f, s3 = 0.f;
    for (int k = 0; k < 128; k += 4) {
        s0 += w1r[k + 0] * encW[(size_t)(k + 0) * 128 + j];
        s1 += w1r[k + 1] * encW[(size_t)(k + 1) * 128 + j];
        s2 += w1r[k + 2] * encW[(size_t)(k + 2) * 128 + j];
        s3 += w1r[k + 3] * encW[(size_t)(k + 3) * 128 + j];
    }
    Wfb[(size_t)i * 128 + j] = __float2bfloat16((s0 + s1) + (s2 + s3));
    W2b[(size_t)i * 128 + j] = __float2bfloat16(W2[(size_t)i * 128 + j]);
    if (i < 48) decWb[(size_t)i * 128 + j] = __float2bfloat16(i < 40 ? decW[(size_t)i * 128 + j] : 0.f);
    // bf[i] = sum_k W1[i][k]*encb[k]
    float t = w1r[j] * encb[j];
#pragma unroll
    for (int o = 32; o; o >>= 1) t += __shfl_down(t, o);
    __shared__ float red[2];
    if ((j & 63) == 0) red[j >> 6] = t;
    __syncthreads();
    if (j == 0) bff[i] = red[0] + red[1];
}

__device__ inline bf16x8 cvt8(float4 lo, float4 hi) {
    union { unsigned short u[8]; bf16x8 v; } t;
    t.u[0] = __builtin_bit_cast(unsigned short, __float2bfloat16(lo.x));
    t.u[1] = __builtin_bit_cast(unsigned short, __float2bfloat16(lo.y));
    t.u[2] = __builtin_bit_cast(unsigned short, __float2bfloat16(lo.z));
    t.u[3] = __builtin_bit_cast(unsigned short, __float2bfloat16(lo.w));
    t.u[4] = __builtin_bit_cast(unsigned short, __float2bfloat16(hi.x));
    t.u[5] = __builtin_bit_cast(unsigned short, __float2bfloat16(hi.y));
    t.u[6] = __builtin_bit_cast(unsigned short, __float2bfloat16(hi.z));
    t.u[7] = __builtin_bit_cast(unsigned short, __float2bfloat16(hi.w));
    return t.v;
}

// ---------------- GEMM: out[M x 128] = rowscale * (A[M x 128] @ W^T + bias) ----------------
// 32 rows/wave, 128 rows/block. SCALE: multiply row r by dscale[r] (pre-folds
// the GCN source normalization dinv[src] so agg needs no per-edge weights).
template<bool A_F32, bool SCALE>
__global__ __launch_bounds__(256) void gemm_k128(const void* __restrict__ Ain,
                                                 const __hip_bfloat16* __restrict__ W,
                                                 const float* __restrict__ bias,
                                                 const float* __restrict__ dscale,
                                                 __hip_bfloat16* __restrict__ out, int M) {
    int lane = threadIdx.x & 63;
    int wave = threadIdx.x >> 6;
    int row0 = blockIdx.x * 128 + wave * 32;
    int kgrp = lane >> 4, cl = lane & 15;

    bf16x8 afrag[2][4];
#pragma unroll
    for (int rt = 0; rt < 2; ++rt) {
        int ar = row0 + rt * 16 + cl;
        if (ar >= M) ar = M - 1;
        if (A_F32) {
            const float* Ar = (const float*)Ain + (size_t)ar * 128;
#pragma unroll
            for (int c = 0; c < 4; ++c) {
                const float4* q = reinterpret_cast<const float4*>(Ar + (4 * c + kgrp) * 8);
                afrag[rt][c] = cvt8(q[0], q[1]);
            }
        } else {
            const bf16x8* Ar = reinterpret_cast<const bf16x8*>((const __hip_bfloat16*)Ain + (size_t)ar * 128);
#pragma unroll
            for (int c = 0; c < 4; ++c) afrag[rt][c] = Ar[4 * c + kgrp];
        }
    }

    f32x4 acc[2][8];
#pragma unroll
    for (int rt = 0; rt < 2; ++rt)
#pragma unroll
        for (int t = 0; t < 8; ++t) acc[rt][t] = {0.f, 0.f, 0.f, 0.f};

#pragma unroll
    for (int c = 0; c < 4; ++c) {
#pragma unroll
        for (int t = 0; t < 8; ++t) {
            bf16x8 bfrag = reinterpret_cast<const bf16x8*>(W + (size_t)(t * 16 + cl) * 128)[4 * c + kgrp];
            acc[0][t] = __builtin_amdgcn_mfma_f32_16x16x32_bf16(afrag[0][c], bfrag, acc[0][t], 0, 0, 0);
            acc[1][t] = __builtin_amdgcn_mfma_f32_16x16x32_bf16(afrag[1][c], bfrag, acc[1][t], 0, 0, 0);
        }
    }

#pragma unroll
    for (int rt = 0; rt < 2; ++rt) {
        int rbase = row0 + rt * 16 + kgrp * 4;
#pragma unroll
        for (int i = 0; i < 4; ++i) {
            int r = rbase + i;
            float sc = 1.f;
            if (SCALE) sc = dscale[(r < M) ? r : (M - 1)];
#pragma unroll
            for (int t = 0; t < 8; ++t) {
                int col = t * 16 + cl;
                float v = acc[rt][t][i] + (bias ? bias[col] : 0.f);
                if (SCALE) v *= sc;
                unsigned int uv = __builtin_bit_cast(unsigned short, __float2bfloat16(v));
                unsigned int pv = (unsigned int)__shfl_xor((int)uv, 1);
                if (!(lane & 1) && r < M)
                    *reinterpret_cast<unsigned int*>(out + (size_t)r * 128 + col) = (uv & 0xffffu) | (pv << 16);
            }
        }
    }
}

// ---------------- aggregation: out[d] = relu(dinv[d]*(sum_s h'[s] + h'[d]) + b) ----------------
// h' rows are pre-scaled by dinv (GEMM epilogue). Wave-uniform scalar CSR walk:
// csr_src[j] indices are SGPR loads (no shuffles, no per-edge VALU beyond cvt+add).
__global__ __launch_bounds__(256) void agg_kernel(const __hip_bfloat16* __restrict__ h,
                                                  const int* __restrict__ csr_src,
                                                  const int* __restrict__ offsets,
                                                  const float* __restrict__ dinv,
                                                  const float* __restrict__ bias,
                                                  __hip_bfloat16* __restrict__ out, int N) {
    int wid  = (blockIdx.x * blockDim.x + threadIdx.x) >> 6;
    int lane = threadIdx.x & 63;
    if (wid >= N) return;
    int d = __builtin_amdgcn_readfirstlane(wid);
    int bc = lane * 2;

    unsigned q0 = *reinterpret_cast<const unsigned*>(&h[(size_t)d * 128 + bc]);  // self (pre-scaled)
    float ax[8], ay[8];
    ax[0] = __builtin_bit_cast(float, q0 << 16);
    ay[0] = __builtin_bit_cast(float, q0 & 0xffff0000u);
#pragma unroll
    for (int k = 1; k < 8; ++k) { ax[k] = 0.f; ay[k] = 0.f; }

    int j0 = __builtin_amdgcn_readfirstlane(offsets[d]);
    int j1 = __builtin_amdgcn_readfirstlane(offsets[d + 1]);
    int j = j0;
    for (; j + 8 <= j1; j += 8) {
        int s[8];
#pragma unroll
        for (int k = 0; k < 8; ++k) s[k] = csr_src[j + k];     // uniform -> SGPR loads
        unsigned q[8];
#pragma unroll
        for (int k = 0; k < 8; ++k)
            q[k] = *reinterpret_cast<const unsigned*>(&h[(size_t)s[k] * 128 + bc]);
#pragma unroll
        for (int k = 0; k < 8; ++k) {
            ax[k] += __builtin_bit_cast(float, q[k] << 16);
            ay[k] += __builtin_bit_cast(float, q[k] & 0xffff0000u);
        }
    }
    for (; j < j1; ++j) {
        int s0 = csr_src[j];
        unsigned q1 = *reinterpret_cast<const unsigned*>(&h[(size_t)s0 * 128 + bc]);
        ax[0] += __builtin_bit_cast(float, q1 << 16);
        ay[0] += __builtin_bit_cast(float, q1 & 0xffff0000u);
    }

    float sx = ((ax[0] + ax[1]) + (ax[2] + ax[3])) + ((ax[4] + ax[5]) + (ax[6] + ax[7]));
    float sy = ((ay[0] + ay[1]) + (ay[2] + ay[3])) + ((ay[4] + ay[5]) + (ay[6] + ay[7]));
    float dd = dinv[d];
    float2 bb = *reinterpret_cast<const float2*>(&bias[bc]);
    float ox = fmaxf(dd * sx + bb.x, 0.f);
    float oy = fmaxf(dd * sy + bb.y, 0.f);
    unsigned ow = (unsigned)__builtin_bit_cast(unsigned short, __float2bfloat16(ox)) |
                  ((unsigned)__builtin_bit_cast(unsigned short, __float2bfloat16(oy)) << 16);
    *reinterpret_cast<unsigned*>(&out[(size_t)d * 128 + bc]) = ow;
}

// ---------------- fused decoder GEMM + log_softmax ----------------
__global__ __launch_bounds__(256) void dec_softmax_kernel(const __hip_bfloat16* __restrict__ A,
                                                          const __hip_bfloat16* __restrict__ Wd,
                                                          const float* __restrict__ bd,
                                                          float* __restrict__ out, int M) {
    int lane = threadIdx.x & 63;
    int wid  = (blockIdx.x * blockDim.x + threadIdx.x) >> 6;
    int row0 = wid * 16;
    if (row0 >= M) return;
    int kgrp = lane >> 4, cl = lane & 15;

    int ar = row0 + cl;
    if (ar >= M) ar = M - 1;
    const bf16x8* Ar = reinterpret_cast<const bf16x8*>(A + (size_t)ar * 128);
    bf16x8 afrag[4];
#pragma unroll
    for (int c = 0; c < 4; ++c) afrag[c] = Ar[4 * c + kgrp];

    f32x4 acc[3];
#pragma unroll
    for (int t = 0; t < 3; ++t) acc[t] = {0.f, 0.f, 0.f, 0.f};
#pragma unroll
    for (int c = 0; c < 4; ++c)
#pragma unroll
        for (int t = 0; t < 3; ++t) {
            bf16x8 bfrag = reinterpret_cast<const bf16x8*>(Wd + (size_t)(t * 16 + cl) * 128)[4 * c + kgrp];
            acc[t] = __builtin_amdgcn_mfma_f32_16x16x32_bf16(afrag[c], bfrag, acc[t], 0, 0, 0);
        }

    float v[3][4];
#pragma unroll
    for (int t = 0; t < 3; ++t) {
        int col = t * 16 + cl;
        float bv = (col < 40) ? bd[col] : 0.f;
#pragma unroll
        for (int i = 0; i < 4; ++i)
            v[t][i] = (col < 40) ? (acc[t][i] + bv) : -INFINITY;
    }

#pragma unroll
    for (int i = 0; i < 4; ++i) {
        float m = fmaxf(fmaxf(v[0][i], v[1][i]), v[2][i]);
#pragma unroll
        for (int o = 1; o < 16; o <<= 1) m = fmaxf(m, __shfl_xor(m, o));
        float s = 0.f;
#pragma unroll
        for (int t = 0; t < 3; ++t) s += (v[t][i] > -INFINITY) ? __expf(v[t][i] - m) : 0.f;
#pragma unroll
        for (int o = 1; o < 16; o <<= 1) s += __shfl_xor(s, o);
        float lse = __logf(s);
        int r = row0 + kgrp * 4 + i;
        if (r < M) {
#pragma unroll
            for (int t = 0; t < 3; ++t) {
                int col = t * 16 + cl;
                if (col < 40) out[(size_t)r * 40 + col] = v[t][i] - m - lse;
            }
        }
    }
}

extern "C" void kernel_launch(void* const* d_in, const int* in_sizes, int n_in,
                              void* d_out, int out_size, void* d_ws, size_t ws_size,
                              hipStream_t stream) {
    const float* X    = (const float*)d_in[0];
    const int*   ei   = (const int*)d_in[1];
    const float* encW = (const float*)d_in[2];
    const float* encb = (const float*)d_in[3];
    const float* W1   = (const float*)d_in[4];
    const float* b1   = (const float*)d_in[5];
    const float* W2   = (const float*)d_in[6];
    const float* b2   = (const float*)d_in[7];
    const float* decW = (const float*)d_in[8];
    const float* decb = (const float*)d_in[9];

    const int N = in_sizes[0] / 128;
    const int E = in_sizes[1] / 2;
    const int* src = ei;
    const int* dst = ei + E;

    int shift = 7;
    while ((((N - 1) >> shift) + 1) > 1024) ++shift;
    const int NBK = ((N - 1) >> shift) + 1;

    uint8_t* p = (uint8_t*)d_ws;
    auto carve = [&](size_t bytes) -> void* {
        uint8_t* r = p;
        p += (bytes + 255) & ~(size_t)255;
        return (void*)r;
    };
    int*   offsets = (int*)carve((size_t)(N + 1) * 4);
    float* dinv    = (float*)carve((size_t)N * 4);
    int*   bhist   = (int*)carve(1025 * 4);
    int*   bbase   = (int*)carve(1025 * 4);
    int*   bcur    = (int*)carve(1024 * 4);
    int*   csr_src = (int*)carve((size_t)E * 4);
    __hip_bfloat16* Wfb   = (__hip_bfloat16*)carve(16384 * 2);
    __hip_bfloat16* W2b   = (__hip_bfloat16*)carve(16384 * 2);
    __hip_bfloat16* decWb = (__hip_bfloat16*)carve(48 * 128 * 2);
    float*          bff   = (float*)carve(128 * 4);
    __hip_bfloat16* xb    = (__hip_bfloat16*)carve((size_t)N * 128 * 2);
    __hip_bfloat16* hb    = (__hip_bfloat16*)carve((size_t)N * 128 * 2);
    uint2* binned = (uint2*)xb;   // dead before xb is first written (by agg1)

    // --- weight prep (independent of graph) ---
    prep_weights_kernel<<<128, 128, 0, stream>>>(W1, encW, encb, W2, decW, Wfb, bff, W2b, decWb);

    // --- graph structure ---
    hipMemsetAsync(bhist, 0, (size_t)NBK * 4, stream);
    bucket_hist_kernel<<<(E + 4095) / 4096, 256, 0, stream>>>(dst, bhist, E, NBK, shift);
    bucket_scan_kernel<<<1, 256, 0, stream>>>(bhist, bbase, bcur, NBK, &offsets[N], E);
    bin_edges_kernel<<<(E + 8191) / 8192, 256, 0, stream>>>(src, dst, bcur, binned, E, NBK, shift);
    bucket_build_kernel<<<NBK, 256, 0, stream>>>(binned, bbase, csr_src, offsets, dinv, N, shift);

    int gblocks = (N + 127) / 128;
    // fused encoder+conv1 linear: hb = dinv[r] * (X @ Wf^T + bf)   [bf16]
    gemm_k128<true, true><<<gblocks, 256, 0, stream>>>(X, Wfb, bff, dinv, hb, N);
    agg_kernel<<<(N + 3) / 4, 256, 0, stream>>>(hb, csr_src, offsets, dinv, b1, xb, N);
    // conv2 linear: hb = dinv[r] * (xb @ W2^T)
    gemm_k128<false, true><<<gblocks, 256, 0, stream>>>(xb, W2b, nullptr, dinv, hb, N);
    agg_kernel<<<(N + 3) / 4, 256, 0, stream>>>(hb, csr_src, offsets, dinv, b2, xb, N);
    // decoder + log_softmax fused
    dec_softmax_kernel<<<(N + 63) / 64, 256, 0, stream>>>(xb, decWb, decb, (float*)d_out, N);
}